// Round 4
// baseline (773.312 us; speedup 1.0000x reference)
//
#include <hip/hip_runtime.h>
#include <math.h>

#define N_ATOMS 40000
#define N_EDGES 640000
#define NB      128
#define NRBF    20
#define NLAYERS 3
#define CUTOFF  5.0f
#define DELTA   (CUTOFF / 19.0f)
#define RBF_COEFF (-0.5f / (DELTA * DELTA))
#define LN2F    0.69314718055994531f

#define KTAB    2048                    // lerp intervals over [0, CUTOFF]
#define TSCALE  ((float)KTAB / CUTOFF)
#define EPB     256                     // edges per block (4 waves x 64)

typedef __attribute__((ext_vector_type(8))) short bf16x8;
typedef __attribute__((ext_vector_type(4))) short bf16x4;
typedef __attribute__((ext_vector_type(4))) float fx4;

__device__ __forceinline__ float ssp_f(float x) {
    return fmaxf(x, 0.f) + __logf(1.f + __expf(-fabsf(x))) - LN2F;
}

__device__ __forceinline__ unsigned short bf16_rne(float x) {
    unsigned u = __float_as_uint(x);
    unsigned r = u + 0x7fffu + ((u >> 16) & 1u);
    return (unsigned short)(r >> 16);
}

// round-to-nearest-even split of fp32 into hi+lo bf16 (as raw short bits)
__device__ __forceinline__ void split_bf16(float x, short& h, short& l) {
    unsigned u = __float_as_uint(x);
    unsigned r = (u + 0x7fffu + ((u >> 16) & 1u)) & 0xffff0000u;
    h = (short)(r >> 16);
    float lf = x - __uint_as_float(r);
    unsigned u2 = __float_as_uint(lf);
    unsigned r2 = u2 + 0x7fffu + ((u2 >> 16) & 1u);
    l = (short)(r2 >> 16);
}

// bf16 (in low/high 16 bits of a uint) -> float
__device__ __forceinline__ float bfl(unsigned u) { return __uint_as_float(u << 16); }
__device__ __forceinline__ float bfh(unsigned u) { return __uint_as_float(u & 0xffff0000u); }

__global__ __launch_bounds__(256) void k_zero(float* __restrict__ p, int n) {
    int i = blockIdx.x * blockDim.x + threadIdx.x;
    if (i < n) p[i] = 0.f;
}

__global__ __launch_bounds__(256) void k_embed(const int* __restrict__ z,
                                               const float* __restrict__ emb,
                                               float* __restrict__ x) {
    int idx = blockIdx.x * blockDim.x + threadIdx.x;
    if (idx < N_ATOMS * NB) {
        int n = idx >> 7, f = idx & 127;
        x[idx] = emb[z[n] * NB + f];
    }
}

__global__ __launch_bounds__(256) void k_dist(const float* __restrict__ r_ij,
                                              float* __restrict__ D) {
    int e = blockIdx.x * blockDim.x + threadIdx.x;
    if (e < N_EDGES) {
        float xx = r_ij[e * 3 + 0];
        float yy = r_ij[e * 3 + 1];
        float zz = r_ij[e * 3 + 2];
        D[e] = sqrtf(xx * xx + yy * yy + zz * zz);
    }
}

// Precompute per-weight LDS images: W^T split into hi/lo bf16, laid out
// [chunk kc][col][klocal ^ ((col&7)<<3)] so GEMM blocks copy chunks linearly.
__global__ __launch_bounds__(256) void k_prep(const float* __restrict__ in2f,
                                              const float* __restrict__ oW1,
                                              const float* __restrict__ oW2,
                                              short* __restrict__ Wimg) {
    int w = blockIdx.x;
    int layer = w / 3, which = w % 3;
    const float* W = (which == 0 ? in2f : which == 1 ? oW1 : oW2)
                     + (size_t)layer * NB * NB;
    short* hi = Wimg + (size_t)w * 32768;
    short* lo = hi + 16384;
    for (int i = threadIdx.x; i < NB * NB; i += 256) {
        int k = i >> 7, col = i & 127;
        short h, l;
        split_bf16(W[i], h, l);
        int kc = k >> 6, kl = k & 63;
        int idx = kc * 8192 + col * 64 + (kl ^ ((col & 7) << 3));
        hi[idx] = h;
        lo[idx] = l;
    }
}

// Build Tab[p][f] = (ssp(rbf(d_p)@W1+b1)@W2+b2) * rcut(d_p), fp32 scratch rows.
__global__ __launch_bounds__(128) void k_table(const float* __restrict__ W1,
                                               const float* __restrict__ b1,
                                               const float* __restrict__ W2,
                                               const float* __restrict__ b2,
                                               float* __restrict__ Tab) {
    __shared__ float t_lds[NB];
    int p = blockIdx.x, f = threadIdx.x;
    float d = (float)p * (CUTOFF / (float)KTAB);
    if (p >= KTAB) {
        Tab[(size_t)p * NB + f] = 0.f;
        return;
    }
    float a = b1[f];
    #pragma unroll
    for (int r = 0; r < NRBF; ++r) {
        float dr = d - (float)r * DELTA;
        a += __expf(RBF_COEFF * dr * dr) * W1[r * NB + f];
    }
    t_lds[f] = ssp_f(a);
    __syncthreads();
    float w = b2[f];
    #pragma unroll 4
    for (int k = 0; k < NB; ++k) w += t_lds[k] * W2[k * NB + f];
    float rc = 0.5f * (__cosf(d * ((float)M_PI / CUTOFF)) + 1.f);
    Tab[(size_t)p * NB + f] = w * rc;
}

// Pack fp32 Tab rows into bf16 value+delta quads:
// TabP[k*256 + (f>>2)*8 + (f&3)] = bf16(T[k][f]); +4 -> bf16(T[k+1][f]-T[k][f])
__global__ __launch_bounds__(128) void k_pack(const float* __restrict__ Tab,
                                              unsigned short* __restrict__ TabP) {
    int k = blockIdx.x, f = threadIdx.x;
    float v = Tab[(size_t)k * NB + f];
    float dl = Tab[(size_t)(k + 1) * NB + f] - v;
    int o = k * 256 + ((f >> 2) << 3) + (f & 3);
    TabP[o]     = bf16_rne(v);
    TabP[o + 4] = bf16_rne(dl);
}

// Split-bf16 MFMA GEMM: Out = A[40000x128] @ W[128x128] (+bias, +act, +accum).
// MODE 0: OutB(bf16) = A@W       (no bias)
// MODE 1: Out = ssp(A@W+b)
// MODE 2: Out += A@W+b
template<int MODE>
__global__ __launch_bounds__(256) void k_mfma_gemm(const float* __restrict__ A,
                                                   const short* __restrict__ Wimg,
                                                   const float* __restrict__ bias,
                                                   float* __restrict__ Out) {
    __shared__ short Ah[64 * 64], Al[64 * 64];     // 8 KB + 8 KB
    __shared__ short Wh[128 * 64], Wl[128 * 64];   // 16 KB + 16 KB
    int tid = threadIdx.x;
    int wave = tid >> 6, lane = tid & 63;
    int wr = (wave & 1) * 32;
    int wc = (wave >> 1) * 64;
    int row0 = blockIdx.x * 64;

    fx4 acc[2][4];
    #pragma unroll
    for (int s = 0; s < 2; ++s)
        #pragma unroll
        for (int c = 0; c < 4; ++c)
            acc[s][c] = (fx4){0.f, 0.f, 0.f, 0.f};

    const short* imgh = Wimg;
    const short* imgl = Wimg + 16384;

    for (int kc = 0; kc < 2; ++kc) {
        if (kc) __syncthreads();
        #pragma unroll
        for (int it = 0; it < 4; ++it) {
            int idx4 = tid + it * 256;
            int r = idx4 >> 4, kq = (idx4 & 15) << 2;
            float4 v = *(const float4*)(A + (size_t)(row0 + r) * NB + kc * 64 + kq);
            bf16x4 hs, ls;
            const float* vf = (const float*)&v;
            #pragma unroll
            for (int j = 0; j < 4; ++j) {
                short h, l;
                split_bf16(vf[j], h, l);
                hs[j] = h; ls[j] = l;
            }
            int wi = r * 64 + (kq ^ ((r & 7) << 3));
            *(bf16x4*)(Ah + wi) = hs;
            *(bf16x4*)(Al + wi) = ls;
        }
        {
            const bf16x8* sh = (const bf16x8*)(imgh + kc * 8192);
            const bf16x8* sl = (const bf16x8*)(imgl + kc * 8192);
            bf16x8* dh = (bf16x8*)Wh;
            bf16x8* dl = (bf16x8*)Wl;
            #pragma unroll
            for (int it = 0; it < 4; ++it) {
                int i = tid + it * 256;
                dh[i] = sh[i];
                dl[i] = sl[i];
            }
        }
        __syncthreads();
        #pragma unroll
        for (int ks = 0; ks < 2; ++ks) {
            int kb = ks * 32 + (lane >> 4) * 8;
            bf16x8 a_h[2], a_l[2];
            #pragma unroll
            for (int s = 0; s < 2; ++s) {
                int r = wr + s * 16 + (lane & 15);
                int idx = r * 64 + (kb ^ ((r & 7) << 3));
                a_h[s] = *(const bf16x8*)(Ah + idx);
                a_l[s] = *(const bf16x8*)(Al + idx);
            }
            #pragma unroll
            for (int c = 0; c < 4; ++c) {
                int col = wc + c * 16 + (lane & 15);
                int idx = col * 64 + (kb ^ ((col & 7) << 3));
                bf16x8 b_h = *(const bf16x8*)(Wh + idx);
                bf16x8 b_l = *(const bf16x8*)(Wl + idx);
                #pragma unroll
                for (int s = 0; s < 2; ++s) {
                    acc[s][c] = __builtin_amdgcn_mfma_f32_16x16x32_bf16(a_h[s], b_l, acc[s][c], 0, 0, 0);
                    acc[s][c] = __builtin_amdgcn_mfma_f32_16x16x32_bf16(a_l[s], b_h, acc[s][c], 0, 0, 0);
                    acc[s][c] = __builtin_amdgcn_mfma_f32_16x16x32_bf16(a_h[s], b_h, acc[s][c], 0, 0, 0);
                }
            }
        }
    }
    #pragma unroll
    for (int s = 0; s < 2; ++s) {
        #pragma unroll
        for (int c = 0; c < 4; ++c) {
            int colg = wc + c * 16 + (lane & 15);
            float bv = (MODE > 0) ? bias[colg] : 0.f;
            #pragma unroll
            for (int reg = 0; reg < 4; ++reg) {
                int rowg = row0 + wr + s * 16 + (lane >> 4) * 4 + reg;
                float v = acc[s][c][reg];
                size_t o = (size_t)rowg * NB + colg;
                if (MODE == 0)      ((unsigned short*)Out)[o] = bf16_rne(v);
                else if (MODE == 1) Out[o] = ssp_f(v + bv);
                else                Out[o] += v + bv;
            }
        }
    }
}

// Edge kernel: 1 wave = 64 contiguous sorted edges, 2 edges per iteration
// (lanes 0-31 even offsets, 32-63 odd). Lane covers a feature quad (float4 acc).
// wij = lerp from packed bf16 value+delta table (one 16B load); H gathered bf16.
__global__ __launch_bounds__(256) void k_edge(const float* __restrict__ D,
                                              const int* __restrict__ idx_i,
                                              const int* __restrict__ idx_j,
                                              const uint2* __restrict__ HBv,
                                              const uint4* __restrict__ TabPv,
                                              float* __restrict__ AGG) {
    __shared__ float d_s[EPB];
    __shared__ int   i_s[EPB];
    __shared__ int   j_s[EPB];
    int tid = threadIdx.x;
    int e0 = blockIdx.x * EPB;
    d_s[tid] = D[e0 + tid];
    i_s[tid] = idx_i[e0 + tid];
    j_s[tid] = idx_j[e0 + tid];
    __syncthreads();

    int wave = tid >> 6, lane = tid & 63;
    int fq = lane & 31;                       // feature quad: features 4fq..4fq+3
    int base = (wave << 6) + (lane >> 5);     // even/odd subsequence start

    float a0 = 0.f, a1 = 0.f, a2 = 0.f, a3 = 0.f;
    int cur = -1;

    #pragma unroll 4
    for (int t = 0; t < 32; ++t) {
        int eo = base + 2 * t;
        float d  = d_s[eo];
        int   ia = i_s[eo];
        int   ja = j_s[eo];

        float u = d * TSCALE;
        int   k = (int)u;
        k = (k > KTAB) ? KTAB : k;            // row KTAB is {0,0} -> w = 0
        float fr = u - (float)k;

        uint4 tp = TabPv[(size_t)k * 32 + fq];
        uint2 hq = HBv[(size_t)ja * 32 + fq];

        float w0 = fmaf(fr, bfl(tp.z), bfl(tp.x));
        float w1 = fmaf(fr, bfh(tp.z), bfh(tp.x));
        float w2 = fmaf(fr, bfl(tp.w), bfl(tp.y));
        float w3 = fmaf(fr, bfh(tp.w), bfh(tp.y));

        if (ia != cur) {                      // uniform per half-wave
            if (cur >= 0) {
                float* p = AGG + (size_t)cur * NB + fq * 4;
                atomicAdd(p + 0, a0);
                atomicAdd(p + 1, a1);
                atomicAdd(p + 2, a2);
                atomicAdd(p + 3, a3);
            }
            a0 = a1 = a2 = a3 = 0.f;
            cur = ia;
        }
        a0 = fmaf(bfl(hq.x), w0, a0);
        a1 = fmaf(bfh(hq.x), w1, a1);
        a2 = fmaf(bfl(hq.y), w2, a2);
        a3 = fmaf(bfh(hq.y), w3, a3);
    }
    if (cur >= 0) {
        float* p = AGG + (size_t)cur * NB + fq * 4;
        atomicAdd(p + 0, a0);
        atomicAdd(p + 1, a1);
        atomicAdd(p + 2, a2);
        atomicAdd(p + 3, a3);
    }
}

extern "C" void kernel_launch(void* const* d_in, const int* in_sizes, int n_in,
                              void* d_out, int out_size, void* d_ws, size_t ws_size,
                              hipStream_t stream) {
    const int*   z    = (const int*)  d_in[0];
    const float* rij  = (const float*)d_in[1];
    const int*   ii   = (const int*)  d_in[2];
    const int*   jj   = (const int*)  d_in[3];
    const float* emb  = (const float*)d_in[4];
    const float* in2f = (const float*)d_in[5];
    const float* fW1  = (const float*)d_in[6];
    const float* fb1  = (const float*)d_in[7];
    const float* fW2  = (const float*)d_in[8];
    const float* fb2  = (const float*)d_in[9];
    const float* oW1  = (const float*)d_in[10];
    const float* ob1  = (const float*)d_in[11];
    const float* oW2  = (const float*)d_in[12];
    const float* ob2  = (const float*)d_in[13];

    const int NXF = N_ATOMS * NB;

    float* X   = (float*)d_out;
    // Union buffer U (20.5 MB) time-multiplexes: fp32 Tab scratch -> bf16 H -> fp32 T
    float* U   = (float*)d_ws;
    float* AGG = U + NXF;
    float* D   = AGG + NXF;
    unsigned short* TabP = (unsigned short*)(D + N_EDGES);          // (KTAB+1)*256
    short* Wimg = (short*)(TabP + (size_t)(KTAB + 1) * 256);        // 9 x 32768

    float* Tab = U;                         // [KTAB+2][NB] fp32 (dead after k_pack)
    unsigned short* HB = (unsigned short*)U; // [N_ATOMS][NB] bf16 (dead after k_edge)
    float* T = U;                           // [N_ATOMS][NB] fp32 (GEMM1 -> GEMM2)

    k_embed<<<(NXF + 255) / 256, 256, 0, stream>>>(z, emb, X);
    k_dist<<<(N_EDGES + 255) / 256, 256, 0, stream>>>(rij, D);
    k_prep<<<9, 256, 0, stream>>>(in2f, oW1, oW2, Wimg);

    for (int l = 0; l < NLAYERS; ++l) {
        const short* img_in2f = Wimg + (size_t)(l * 3 + 0) * 32768;
        const short* img_oW1  = Wimg + (size_t)(l * 3 + 1) * 32768;
        const short* img_oW2  = Wimg + (size_t)(l * 3 + 2) * 32768;

        k_zero<<<(NXF + 255) / 256, 256, 0, stream>>>(AGG, NXF);
        k_table<<<KTAB + 2, 128, 0, stream>>>(fW1 + (size_t)l * NRBF * NB,
                                              fb1 + (size_t)l * NB,
                                              fW2 + (size_t)l * NB * NB,
                                              fb2 + (size_t)l * NB,
                                              Tab);
        k_pack<<<KTAB + 1, 128, 0, stream>>>(Tab, TabP);
        // HB = bf16(X @ in2f)   (overwrites Tab scratch; Tab already packed)
        k_mfma_gemm<0><<<N_ATOMS / 64, 256, 0, stream>>>(X, img_in2f, nullptr, (float*)HB);
        // AGG = segment_sum(HB[j] * lerp(TabP, d))
        k_edge<<<N_EDGES / EPB, 256, 0, stream>>>(D, ii, jj,
                                                  (const uint2*)HB,
                                                  (const uint4*)TabP,
                                                  AGG);
        // T = ssp(AGG @ oW1 + b1)   (overwrites HB; HB dead)
        k_mfma_gemm<1><<<N_ATOMS / 64, 256, 0, stream>>>(AGG, img_oW1,
                                                         ob1 + (size_t)l * NB, T);
        // X += T @ oW2 + b2
        k_mfma_gemm<2><<<N_ATOMS / 64, 256, 0, stream>>>(T, img_oW2,
                                                         ob2 + (size_t)l * NB, X);
    }
}

// Round 5
// 355.893 us; speedup vs baseline: 2.1729x; 2.1729x over previous
//
#include <hip/hip_runtime.h>
#include <math.h>

#define N_ATOMS 40000
#define N_EDGES 640000
#define NB      128
#define NRBF    20
#define NLAYERS 3
#define CUTOFF  5.0f
#define DELTA   (CUTOFF / 19.0f)
#define RBF_COEFF (-0.5f / (DELTA * DELTA))
#define LN2F    0.69314718055994531f

#define KTAB    2048                    // lerp intervals over [0, CUTOFF]
#define TSCALE  ((float)KTAB / CUTOFF)
#define EPB     256                     // edges per block (4 waves x 64)

typedef __attribute__((ext_vector_type(8))) short bf16x8;
typedef __attribute__((ext_vector_type(4))) short bf16x4;
typedef __attribute__((ext_vector_type(4))) float fx4;

__device__ __forceinline__ float ssp_f(float x) {
    return fmaxf(x, 0.f) + __logf(1.f + __expf(-fabsf(x))) - LN2F;
}

__device__ __forceinline__ unsigned short bf16_rne(float x) {
    unsigned u = __float_as_uint(x);
    unsigned r = u + 0x7fffu + ((u >> 16) & 1u);
    return (unsigned short)(r >> 16);
}

// round-to-nearest-even split of fp32 into hi+lo bf16 (as raw short bits)
__device__ __forceinline__ void split_bf16(float x, short& h, short& l) {
    unsigned u = __float_as_uint(x);
    unsigned r = (u + 0x7fffu + ((u >> 16) & 1u)) & 0xffff0000u;
    h = (short)(r >> 16);
    float lf = x - __uint_as_float(r);
    unsigned u2 = __float_as_uint(lf);
    unsigned r2 = u2 + 0x7fffu + ((u2 >> 16) & 1u);
    l = (short)(r2 >> 16);
}

// bf16 (in low/high 16 bits of a uint) -> float
__device__ __forceinline__ float bfl(unsigned u) { return __uint_as_float(u << 16); }
__device__ __forceinline__ float bfh(unsigned u) { return __uint_as_float(u & 0xffff0000u); }

__global__ __launch_bounds__(256) void k_zero(float* __restrict__ p, int n) {
    int i = blockIdx.x * blockDim.x + threadIdx.x;
    if (i < n) p[i] = 0.f;
}

__global__ __launch_bounds__(256) void k_embed(const int* __restrict__ z,
                                               const float* __restrict__ emb,
                                               float* __restrict__ x) {
    int idx = blockIdx.x * blockDim.x + threadIdx.x;
    if (idx < N_ATOMS * NB) {
        int n = idx >> 7, f = idx & 127;
        x[idx] = emb[z[n] * NB + f];
    }
}

__global__ __launch_bounds__(256) void k_dist(const float* __restrict__ r_ij,
                                              float* __restrict__ D) {
    int e = blockIdx.x * blockDim.x + threadIdx.x;
    if (e < N_EDGES) {
        float xx = r_ij[e * 3 + 0];
        float yy = r_ij[e * 3 + 1];
        float zz = r_ij[e * 3 + 2];
        D[e] = sqrtf(xx * xx + yy * yy + zz * zz);
    }
}

// Precompute per-weight LDS images: W^T split into hi/lo bf16, laid out
// [chunk kc][col][klocal ^ ((col&7)<<3)] so GEMM blocks copy chunks linearly.
__global__ __launch_bounds__(256) void k_prep(const float* __restrict__ in2f,
                                              const float* __restrict__ oW1,
                                              const float* __restrict__ oW2,
                                              short* __restrict__ Wimg) {
    int w = blockIdx.x;
    int layer = w / 3, which = w % 3;
    const float* W = (which == 0 ? in2f : which == 1 ? oW1 : oW2)
                     + (size_t)layer * NB * NB;
    short* hi = Wimg + (size_t)w * 32768;
    short* lo = hi + 16384;
    for (int i = threadIdx.x; i < NB * NB; i += 256) {
        int k = i >> 7, col = i & 127;
        short h, l;
        split_bf16(W[i], h, l);
        int kc = k >> 6, kl = k & 63;
        int idx = kc * 8192 + col * 64 + (kl ^ ((col & 7) << 3));
        hi[idx] = h;
        lo[idx] = l;
    }
}

// Build Tab[p][f] = (ssp(rbf(d_p)@W1+b1)@W2+b2) * rcut(d_p), fp32 scratch rows.
__global__ __launch_bounds__(128) void k_table(const float* __restrict__ W1,
                                               const float* __restrict__ b1,
                                               const float* __restrict__ W2,
                                               const float* __restrict__ b2,
                                               float* __restrict__ Tab) {
    __shared__ float t_lds[NB];
    int p = blockIdx.x, f = threadIdx.x;
    float d = (float)p * (CUTOFF / (float)KTAB);
    if (p >= KTAB) {
        Tab[(size_t)p * NB + f] = 0.f;
        return;
    }
    float a = b1[f];
    #pragma unroll
    for (int r = 0; r < NRBF; ++r) {
        float dr = d - (float)r * DELTA;
        a += __expf(RBF_COEFF * dr * dr) * W1[r * NB + f];
    }
    t_lds[f] = ssp_f(a);
    __syncthreads();
    float w = b2[f];
    #pragma unroll 4
    for (int k = 0; k < NB; ++k) w += t_lds[k] * W2[k * NB + f];
    float rc = 0.5f * (__cosf(d * ((float)M_PI / CUTOFF)) + 1.f);
    Tab[(size_t)p * NB + f] = w * rc;
}

// Pack fp32 Tab rows into bf16 {val,val,delta,delta} pairs:
// pair p of row k at shorts [k*256 + 4p .. +3] = {v(2p), v(2p+1), d(2p), d(2p+1)}
__global__ __launch_bounds__(128) void k_pack(const float* __restrict__ Tab,
                                              unsigned short* __restrict__ TabP) {
    int k = blockIdx.x, f = threadIdx.x;
    float v = Tab[(size_t)k * NB + f];
    float dl = Tab[(size_t)(k + 1) * NB + f] - v;
    int o = k * 256 + ((f >> 1) << 2) + (f & 1);
    TabP[o]     = bf16_rne(v);
    TabP[o + 2] = bf16_rne(dl);
}

// Split-bf16 MFMA GEMM: Out = A[40000x128] @ W[128x128] (+bias, +act, +accum).
// MODE 0: OutB(bf16) = A@W       (no bias)
// MODE 1: Out = ssp(A@W+b)
// MODE 2: Out += A@W+b
template<int MODE>
__global__ __launch_bounds__(256) void k_mfma_gemm(const float* __restrict__ A,
                                                   const short* __restrict__ Wimg,
                                                   const float* __restrict__ bias,
                                                   float* __restrict__ Out) {
    __shared__ short Ah[64 * 64], Al[64 * 64];     // 8 KB + 8 KB
    __shared__ short Wh[128 * 64], Wl[128 * 64];   // 16 KB + 16 KB
    int tid = threadIdx.x;
    int wave = tid >> 6, lane = tid & 63;
    int wr = (wave & 1) * 32;
    int wc = (wave >> 1) * 64;
    int row0 = blockIdx.x * 64;

    fx4 acc[2][4];
    #pragma unroll
    for (int s = 0; s < 2; ++s)
        #pragma unroll
        for (int c = 0; c < 4; ++c)
            acc[s][c] = (fx4){0.f, 0.f, 0.f, 0.f};

    const short* imgh = Wimg;
    const short* imgl = Wimg + 16384;

    for (int kc = 0; kc < 2; ++kc) {
        if (kc) __syncthreads();
        #pragma unroll
        for (int it = 0; it < 4; ++it) {
            int idx4 = tid + it * 256;
            int r = idx4 >> 4, kq = (idx4 & 15) << 2;
            float4 v = *(const float4*)(A + (size_t)(row0 + r) * NB + kc * 64 + kq);
            bf16x4 hs, ls;
            const float* vf = (const float*)&v;
            #pragma unroll
            for (int j = 0; j < 4; ++j) {
                short h, l;
                split_bf16(vf[j], h, l);
                hs[j] = h; ls[j] = l;
            }
            int wi = r * 64 + (kq ^ ((r & 7) << 3));
            *(bf16x4*)(Ah + wi) = hs;
            *(bf16x4*)(Al + wi) = ls;
        }
        {
            const bf16x8* sh = (const bf16x8*)(imgh + kc * 8192);
            const bf16x8* sl = (const bf16x8*)(imgl + kc * 8192);
            bf16x8* dh = (bf16x8*)Wh;
            bf16x8* dl = (bf16x8*)Wl;
            #pragma unroll
            for (int it = 0; it < 4; ++it) {
                int i = tid + it * 256;
                dh[i] = sh[i];
                dl[i] = sl[i];
            }
        }
        __syncthreads();
        #pragma unroll
        for (int ks = 0; ks < 2; ++ks) {
            int kb = ks * 32 + (lane >> 4) * 8;
            bf16x8 a_h[2], a_l[2];
            #pragma unroll
            for (int s = 0; s < 2; ++s) {
                int r = wr + s * 16 + (lane & 15);
                int idx = r * 64 + (kb ^ ((r & 7) << 3));
                a_h[s] = *(const bf16x8*)(Ah + idx);
                a_l[s] = *(const bf16x8*)(Al + idx);
            }
            #pragma unroll
            for (int c = 0; c < 4; ++c) {
                int col = wc + c * 16 + (lane & 15);
                int idx = col * 64 + (kb ^ ((col & 7) << 3));
                bf16x8 b_h = *(const bf16x8*)(Wh + idx);
                bf16x8 b_l = *(const bf16x8*)(Wl + idx);
                #pragma unroll
                for (int s = 0; s < 2; ++s) {
                    acc[s][c] = __builtin_amdgcn_mfma_f32_16x16x32_bf16(a_h[s], b_l, acc[s][c], 0, 0, 0);
                    acc[s][c] = __builtin_amdgcn_mfma_f32_16x16x32_bf16(a_l[s], b_h, acc[s][c], 0, 0, 0);
                    acc[s][c] = __builtin_amdgcn_mfma_f32_16x16x32_bf16(a_h[s], b_h, acc[s][c], 0, 0, 0);
                }
            }
        }
    }
    #pragma unroll
    for (int s = 0; s < 2; ++s) {
        #pragma unroll
        for (int c = 0; c < 4; ++c) {
            int colg = wc + c * 16 + (lane & 15);
            float bv = (MODE > 0) ? bias[colg] : 0.f;
            #pragma unroll
            for (int reg = 0; reg < 4; ++reg) {
                int rowg = row0 + wr + s * 16 + (lane >> 4) * 4 + reg;
                float v = acc[s][c][reg];
                size_t o = (size_t)rowg * NB + colg;
                if (MODE == 0)      ((unsigned short*)Out)[o] = bf16_rne(v);
                else if (MODE == 1) Out[o] = ssp_f(v + bv);
                else                Out[o] += v + bv;
            }
        }
    }
}

// Edge kernel: 1 wave = 64 contiguous sorted edges, ONE accumulator stream.
// Lane covers 2 features. wij = lerp from packed bf16 {val,delta} table (one
// 8B load/lane); H gathered bf16 (4B/lane). Segment flushes: first and final
// flush of the window may cross window boundaries -> atomic; interior segments
// are exclusive to this wave -> plain float2 store.
__global__ __launch_bounds__(256) void k_edge(const float* __restrict__ D,
                                              const int* __restrict__ idx_i,
                                              const int* __restrict__ idx_j,
                                              const unsigned* __restrict__ HBv,
                                              const uint2* __restrict__ TabPv,
                                              float* __restrict__ AGG) {
    __shared__ float d_s[EPB];
    __shared__ int   i_s[EPB];
    __shared__ int   j_s[EPB];
    int tid = threadIdx.x;
    int e0 = blockIdx.x * EPB;
    d_s[tid] = D[e0 + tid];
    i_s[tid] = idx_i[e0 + tid];
    j_s[tid] = idx_j[e0 + tid];
    __syncthreads();

    int wave = tid >> 6, lane = tid & 63;
    int wbase = wave << 6;

    float ax = 0.f, ay = 0.f;
    int cur = -1;
    int nf = 0;                            // flushes so far in this window

    #pragma unroll 2
    for (int t = 0; t < 64; ++t) {
        int eo = wbase + t;
        float d  = d_s[eo];
        int   ia = i_s[eo];
        int   ja = j_s[eo];

        float u = d * TSCALE;
        int   k = (int)u;
        k = (k > KTAB) ? KTAB : k;         // row KTAB is {0,0} -> w = 0
        float fr = u - (float)k;

        uint2    tp = TabPv[(size_t)k * 64 + lane];
        unsigned hq = HBv[(size_t)ja * 64 + lane];

        float w0 = fmaf(fr, bfl(tp.y), bfl(tp.x));
        float w1 = fmaf(fr, bfh(tp.y), bfh(tp.x));

        if (ia != cur) {                   // wave-uniform branch
            if (cur >= 0) {
                float* p = AGG + (size_t)cur * NB + 2 * lane;
                if (nf == 0) {             // first flush: may extend before window
                    atomicAdd(p + 0, ax);
                    atomicAdd(p + 1, ay);
                } else {                   // interior segment: exclusive, plain store
                    *(float2*)p = make_float2(ax, ay);
                }
                ++nf;
            }
            ax = 0.f; ay = 0.f;
            cur = ia;
        }
        ax = fmaf(bfl(hq), w0, ax);
        ay = fmaf(bfh(hq), w1, ay);
    }
    if (cur >= 0) {                        // final flush: may extend past window
        float* p = AGG + (size_t)cur * NB + 2 * lane;
        atomicAdd(p + 0, ax);
        atomicAdd(p + 1, ay);
    }
}

extern "C" void kernel_launch(void* const* d_in, const int* in_sizes, int n_in,
                              void* d_out, int out_size, void* d_ws, size_t ws_size,
                              hipStream_t stream) {
    const int*   z    = (const int*)  d_in[0];
    const float* rij  = (const float*)d_in[1];
    const int*   ii   = (const int*)  d_in[2];
    const int*   jj   = (const int*)  d_in[3];
    const float* emb  = (const float*)d_in[4];
    const float* in2f = (const float*)d_in[5];
    const float* fW1  = (const float*)d_in[6];
    const float* fb1  = (const float*)d_in[7];
    const float* fW2  = (const float*)d_in[8];
    const float* fb2  = (const float*)d_in[9];
    const float* oW1  = (const float*)d_in[10];
    const float* ob1  = (const float*)d_in[11];
    const float* oW2  = (const float*)d_in[12];
    const float* ob2  = (const float*)d_in[13];

    const int NXF = N_ATOMS * NB;

    float* X   = (float*)d_out;
    // Union buffer U (20.5 MB) time-multiplexes: fp32 Tab scratch -> bf16 H -> fp32 T
    float* U   = (float*)d_ws;
    float* AGG = U + NXF;
    float* D   = AGG + NXF;
    unsigned short* TabP = (unsigned short*)(D + N_EDGES);          // (KTAB+1)*256
    short* Wimg = (short*)(TabP + (size_t)(KTAB + 1) * 256);        // 9 x 32768

    float* Tab = U;                          // [KTAB+2][NB] fp32 (dead after k_pack)
    unsigned short* HB = (unsigned short*)U; // [N_ATOMS][NB] bf16 (dead after k_edge)
    float* T = U;                            // [N_ATOMS][NB] fp32 (GEMM1 -> GEMM2)

    k_embed<<<(NXF + 255) / 256, 256, 0, stream>>>(z, emb, X);
    k_dist<<<(N_EDGES + 255) / 256, 256, 0, stream>>>(rij, D);
    k_prep<<<9, 256, 0, stream>>>(in2f, oW1, oW2, Wimg);

    for (int l = 0; l < NLAYERS; ++l) {
        const short* img_in2f = Wimg + (size_t)(l * 3 + 0) * 32768;
        const short* img_oW1  = Wimg + (size_t)(l * 3 + 1) * 32768;
        const short* img_oW2  = Wimg + (size_t)(l * 3 + 2) * 32768;

        k_zero<<<(NXF + 255) / 256, 256, 0, stream>>>(AGG, NXF);
        k_table<<<KTAB + 2, 128, 0, stream>>>(fW1 + (size_t)l * NRBF * NB,
                                              fb1 + (size_t)l * NB,
                                              fW2 + (size_t)l * NB * NB,
                                              fb2 + (size_t)l * NB,
                                              Tab);
        k_pack<<<KTAB + 1, 128, 0, stream>>>(Tab, TabP);
        // HB = bf16(X @ in2f)   (overwrites Tab scratch; Tab already packed)
        k_mfma_gemm<0><<<N_ATOMS / 64, 256, 0, stream>>>(X, img_in2f, nullptr, (float*)HB);
        // AGG = segment_sum(HB[j] * lerp(TabP, d))
        k_edge<<<N_EDGES / EPB, 256, 0, stream>>>(D, ii, jj,
                                                  (const unsigned*)HB,
                                                  (const uint2*)TabP,
                                                  AGG);
        // T = ssp(AGG @ oW1 + b1)   (overwrites HB; HB dead)
        k_mfma_gemm<1><<<N_ATOMS / 64, 256, 0, stream>>>(AGG, img_oW1,
                                                         ob1 + (size_t)l * NB, T);
        // X += T @ oW2 + b2
        k_mfma_gemm<2><<<N_ATOMS / 64, 256, 0, stream>>>(T, img_oW2,
                                                         ob2 + (size_t)l * NB, X);
    }
}

// Round 6
// 324.530 us; speedup vs baseline: 2.3829x; 1.0966x over previous
//
#include <hip/hip_runtime.h>
#include <math.h>

#define N_ATOMS 40000
#define N_EDGES 640000
#define NB      128
#define NRBF    20
#define NLAYERS 3
#define CUTOFF  5.0f
#define DELTA   (CUTOFF / 19.0f)
#define RBF_COEFF (-0.5f / (DELTA * DELTA))
#define LN2F    0.69314718055994531f

#define KTAB    2048                    // lerp intervals over [0, CUTOFF]
#define TSCALE  ((float)KTAB / CUTOFF)
#define EPB     256                     // edges per block (4 waves x 64)

typedef __attribute__((ext_vector_type(8))) short bf16x8;
typedef __attribute__((ext_vector_type(4))) short bf16x4;
typedef __attribute__((ext_vector_type(4))) float fx4;

__device__ __forceinline__ float ssp_f(float x) {
    return fmaxf(x, 0.f) + __logf(1.f + __expf(-fabsf(x))) - LN2F;
}

__device__ __forceinline__ unsigned short bf16_rne(float x) {
    unsigned u = __float_as_uint(x);
    unsigned r = u + 0x7fffu + ((u >> 16) & 1u);
    return (unsigned short)(r >> 16);
}

__device__ __forceinline__ void split_bf16(float x, short& h, short& l) {
    unsigned u = __float_as_uint(x);
    unsigned r = (u + 0x7fffu + ((u >> 16) & 1u)) & 0xffff0000u;
    h = (short)(r >> 16);
    float lf = x - __uint_as_float(r);
    unsigned u2 = __float_as_uint(lf);
    unsigned r2 = u2 + 0x7fffu + ((u2 >> 16) & 1u);
    l = (short)(r2 >> 16);
}

__device__ __forceinline__ float bfl(unsigned u) { return __uint_as_float(u << 16); }
__device__ __forceinline__ float bfh(unsigned u) { return __uint_as_float(u & 0xffff0000u); }

// ---- shared GEMM building blocks (proven in rounds 3-5) ----

// stage fp32 A-tile chunk (64 rows x 64 k) -> split bf16, swizzled
__device__ __forceinline__ void stage_A_f32(const float* __restrict__ A, int row0, int kc,
                                            short* Ah, short* Al, int tid) {
    #pragma unroll
    for (int it = 0; it < 4; ++it) {
        int idx4 = tid + it * 256;
        int r = idx4 >> 4, kq = (idx4 & 15) << 2;
        float4 v = *(const float4*)(A + (size_t)(row0 + r) * NB + kc * 64 + kq);
        bf16x4 hs, ls;
        const float* vf = (const float*)&v;
        #pragma unroll
        for (int j = 0; j < 4; ++j) {
            short h, l;
            split_bf16(vf[j], h, l);
            hs[j] = h; ls[j] = l;
        }
        int wi = r * 64 + (kq ^ ((r & 7) << 3));
        *(bf16x4*)(Ah + wi) = hs;
        *(bf16x4*)(Al + wi) = ls;
    }
}

// stage pre-swizzled weight chunk image (128 cols x 64 k, hi+lo)
__device__ __forceinline__ void stage_W(const short* __restrict__ imgh,
                                        const short* __restrict__ imgl,
                                        short* Wh, short* Wl, int tid) {
    #pragma unroll
    for (int it = 0; it < 4; ++it) {
        int i = tid + it * 256;
        ((bf16x8*)Wh)[i] = ((const bf16x8*)imgh)[i];
        ((bf16x8*)Wl)[i] = ((const bf16x8*)imgl)[i];
    }
}

// one K=64 chunk of split-bf16 MFMA: acc += A_chunk @ W_chunk
__device__ __forceinline__ void g_compute(const short* AH, const short* AL, int choff,
                                          const short* Wh, const short* Wl,
                                          int wr, int wc, int lane, fx4 acc[2][4]) {
    #pragma unroll
    for (int ks = 0; ks < 2; ++ks) {
        int kb = ks * 32 + (lane >> 4) * 8;
        bf16x8 a_h[2], a_l[2];
        #pragma unroll
        for (int s = 0; s < 2; ++s) {
            int r = wr + s * 16 + (lane & 15);
            int idx = choff + r * 64 + (kb ^ ((r & 7) << 3));
            a_h[s] = *(const bf16x8*)(AH + idx);
            a_l[s] = *(const bf16x8*)(AL + idx);
        }
        #pragma unroll
        for (int c = 0; c < 4; ++c) {
            int col = wc + c * 16 + (lane & 15);
            int idx = col * 64 + (kb ^ ((col & 7) << 3));
            bf16x8 b_h = *(const bf16x8*)(Wh + idx);
            bf16x8 b_l = *(const bf16x8*)(Wl + idx);
            #pragma unroll
            for (int s = 0; s < 2; ++s) {
                acc[s][c] = __builtin_amdgcn_mfma_f32_16x16x32_bf16(a_h[s], b_l, acc[s][c], 0, 0, 0);
                acc[s][c] = __builtin_amdgcn_mfma_f32_16x16x32_bf16(a_l[s], b_h, acc[s][c], 0, 0, 0);
                acc[s][c] = __builtin_amdgcn_mfma_f32_16x16x32_bf16(a_h[s], b_h, acc[s][c], 0, 0, 0);
            }
        }
    }
}

// ---- fused init: embed -> X, dist -> u, weight prep -> Wimg ----
#define I_EMB_BLKS 1250
#define I_DST_BLKS 625
__global__ __launch_bounds__(256) void k_init(const int* __restrict__ z,
                                              const float* __restrict__ emb,
                                              const float* __restrict__ r_ij,
                                              const float* __restrict__ in2f,
                                              const float* __restrict__ oW1,
                                              const float* __restrict__ oW2,
                                              float* __restrict__ X,
                                              float* __restrict__ U,
                                              short* __restrict__ Wimg) {
    int bid = blockIdx.x, tid = threadIdx.x;
    if (bid < I_EMB_BLKS) {
        int base = bid * 4096 + tid * 16;        // 16 floats per thread, within a row
        int row = base >> 7, f0 = base & 127;
        int zz = z[row];
        const float4* src = (const float4*)(emb + (size_t)zz * NB + f0);
        float4* dst = (float4*)(X + base);
        dst[0] = src[0]; dst[1] = src[1]; dst[2] = src[2]; dst[3] = src[3];
    } else if (bid < I_EMB_BLKS + I_DST_BLKS) {
        int e = (bid - I_EMB_BLKS) * 1024 + tid * 4;
        const float4* rv = (const float4*)(r_ij + (size_t)e * 3);
        float4 a = rv[0], b = rv[1], c = rv[2];
        float d0 = sqrtf(a.x * a.x + a.y * a.y + a.z * a.z);
        float d1 = sqrtf(a.w * a.w + b.x * b.x + b.y * b.y);
        float d2 = sqrtf(b.z * b.z + b.w * b.w + c.x * c.x);
        float d3 = sqrtf(c.y * c.y + c.z * c.z + c.w * c.w);
        *(float4*)(U + e) = make_float4(d0 * TSCALE, d1 * TSCALE, d2 * TSCALE, d3 * TSCALE);
    } else {
        int w = bid - (I_EMB_BLKS + I_DST_BLKS);   // 0..8
        int layer = w / 3, which = w % 3;
        const float* W = (which == 0 ? in2f : which == 1 ? oW1 : oW2)
                         + (size_t)layer * NB * NB;
        short* hi = Wimg + (size_t)w * 32768;
        short* lo = hi + 16384;
        for (int i = tid; i < NB * NB; i += 256) {
            int k = i >> 7, col = i & 127;
            short h, l;
            split_bf16(W[i], h, l);
            int kc = k >> 6, kl = k & 63;
            int idx = kc * 8192 + col * 64 + (kl ^ ((col & 7) << 3));
            hi[idx] = h;
            lo[idx] = l;
        }
    }
}

// ---- fused per-layer pre-edge kernel: GEMM0 (HB=bf16(X@in2f)) + zero AGG + table ----
#define A_GEMM_BLKS 625
#define A_ZERO_BLKS 1250
#define A_TAB_BLKS  1025
__global__ __launch_bounds__(256) void k_pre(const float* __restrict__ X,
                                             const short* __restrict__ img0,
                                             unsigned short* __restrict__ HB,
                                             const float* __restrict__ fW1,
                                             const float* __restrict__ fb1,
                                             const float* __restrict__ fW2,
                                             const float* __restrict__ fb2,
                                             unsigned short* __restrict__ TabB,
                                             float* __restrict__ AGG) {
    __shared__ short APOOL[24576];               // 48 KB
    int bid = blockIdx.x, tid = threadIdx.x;

    if (bid < A_GEMM_BLKS) {
        short* Ah = APOOL;
        short* Al = APOOL + 4096;
        short* Wh = APOOL + 8192;
        short* Wl = APOOL + 16384;
        int wave = tid >> 6, lane = tid & 63;
        int wr = (wave & 1) * 32, wc = (wave >> 1) * 64;
        int row0 = bid * 64;
        fx4 acc[2][4];
        #pragma unroll
        for (int s = 0; s < 2; ++s)
            #pragma unroll
            for (int c = 0; c < 4; ++c)
                acc[s][c] = (fx4){0.f, 0.f, 0.f, 0.f};
        for (int kc = 0; kc < 2; ++kc) {
            if (kc) __syncthreads();
            stage_A_f32(X, row0, kc, Ah, Al, tid);
            stage_W(img0 + kc * 8192, img0 + 16384 + kc * 8192, Wh, Wl, tid);
            __syncthreads();
            g_compute(Ah, Al, 0, Wh, Wl, wr, wc, lane, acc);
        }
        #pragma unroll
        for (int s = 0; s < 2; ++s)
            #pragma unroll
            for (int c = 0; c < 4; ++c) {
                int colg = wc + c * 16 + (lane & 15);
                #pragma unroll
                for (int reg = 0; reg < 4; ++reg) {
                    int rowg = row0 + wr + s * 16 + (lane >> 4) * 4 + reg;
                    HB[(size_t)rowg * NB + colg] = bf16_rne(acc[s][c][reg]);
                }
            }
    } else if (bid < A_GEMM_BLKS + A_ZERO_BLKS) {
        int base = (bid - A_GEMM_BLKS) * 4096 + tid * 16;
        float4 zv = make_float4(0.f, 0.f, 0.f, 0.f);
        float4* p = (float4*)(AGG + base);
        p[0] = zv; p[1] = zv; p[2] = zv; p[3] = zv;
    } else {
        int tb = bid - (A_GEMM_BLKS + A_ZERO_BLKS);
        int half = tid >> 7, f = tid & 127;
        int r = tb * 2 + half;                    // 0..2049
        if (r >= KTAB) {                          // block-uniform (rows 2048,2049)
            TabB[(size_t)r * NB + f] = 0;
            return;
        }
        float* tl = (float*)APOOL;                // 2 x 128 floats
        float d = (float)r * (CUTOFF / (float)KTAB);
        float a = fb1[f];
        #pragma unroll
        for (int q = 0; q < NRBF; ++q) {
            float dr = d - (float)q * DELTA;
            a += __expf(RBF_COEFF * dr * dr) * fW1[q * NB + f];
        }
        tl[half * NB + f] = ssp_f(a);
        __syncthreads();
        float w = fb2[f];
        #pragma unroll 4
        for (int k = 0; k < NB; ++k) w += tl[half * NB + k] * fW2[k * NB + f];
        float rc = 0.5f * (__cosf(d * ((float)M_PI / CUTOFF)) + 1.f);
        TabB[(size_t)r * NB + f] = bf16_rne(w * rc);
    }
}

// ---- edge kernel: one accumulator stream/wave, bf16 table rows k,k+1 + bf16 H ----
__global__ __launch_bounds__(256) void k_edge(const float* __restrict__ U,
                                              const int* __restrict__ idx_i,
                                              const int* __restrict__ idx_j,
                                              const unsigned* __restrict__ HBv,
                                              const unsigned* __restrict__ TabU,
                                              float* __restrict__ AGG) {
    __shared__ float u_s[EPB];
    __shared__ int   i_s[EPB];
    __shared__ int   j_s[EPB];
    int tid = threadIdx.x;
    int e0 = blockIdx.x * EPB;
    u_s[tid] = U[e0 + tid];
    i_s[tid] = idx_i[e0 + tid];
    j_s[tid] = idx_j[e0 + tid];
    __syncthreads();

    int wave = tid >> 6, lane = tid & 63;
    int wbase = wave << 6;

    float ax = 0.f, ay = 0.f;
    int cur = -1;
    int nf = 0;

    #pragma unroll 4
    for (int t = 0; t < 64; ++t) {
        int eo = wbase + t;
        float u  = u_s[eo];
        int   ia = i_s[eo];
        int   ja = j_s[eo];

        int k = (int)u;
        k = (k > KTAB) ? KTAB : k;             // rows >= KTAB are zero
        float fr = u - (float)k;

        unsigned v0 = TabU[(size_t)k * 64 + lane];
        unsigned v1 = TabU[(size_t)k * 64 + 64 + lane];
        unsigned hq = HBv[(size_t)ja * 64 + lane];

        float w0 = fmaf(fr, bfl(v1) - bfl(v0), bfl(v0));
        float w1 = fmaf(fr, bfh(v1) - bfh(v0), bfh(v0));

        if (ia != cur) {                       // wave-uniform branch
            if (cur >= 0) {
                float* p = AGG + (size_t)cur * NB + 2 * lane;
                if (nf == 0) {                 // first flush may cross window start
                    atomicAdd(p + 0, ax);
                    atomicAdd(p + 1, ay);
                } else {                       // interior segment: exclusive
                    *(float2*)p = make_float2(ax, ay);
                }
                ++nf;
            }
            ax = 0.f; ay = 0.f;
            cur = ia;
        }
        ax = fmaf(bfl(hq), w0, ax);
        ay = fmaf(bfh(hq), w1, ay);
    }
    if (cur >= 0) {                            // final flush may cross window end
        float* p = AGG + (size_t)cur * NB + 2 * lane;
        atomicAdd(p + 0, ax);
        atomicAdd(p + 1, ay);
    }
}

// ---- fused out-MLP: X += ssp(AGG@W1+b1)@W2 + b2, T kept in LDS ----
__global__ __launch_bounds__(256) void k_outfused(const float* __restrict__ AGG,
                                                  const short* __restrict__ img1,
                                                  const float* __restrict__ b1,
                                                  const short* __restrict__ img2,
                                                  const float* __restrict__ b2,
                                                  float* __restrict__ X) {
    __shared__ short POOL[32768];              // 64 KB
    short* Ah = POOL;                          // GEMM1 A chunk (overlaid by Th later)
    short* Al = POOL + 4096;
    short* Th = POOL;                          // T hi: 2 chunks x 4096
    short* Tl = POOL + 8192;                   // T lo
    short* Wh = POOL + 16384;
    short* Wl = POOL + 24576;

    int tid = threadIdx.x;
    int wave = tid >> 6, lane = tid & 63;
    int wr = (wave & 1) * 32, wc = (wave >> 1) * 64;
    int row0 = blockIdx.x * 64;

    // ---- GEMM1: accT = AGG @ W1 ----
    fx4 accT[2][4];
    #pragma unroll
    for (int s = 0; s < 2; ++s)
        #pragma unroll
        for (int c = 0; c < 4; ++c)
            accT[s][c] = (fx4){0.f, 0.f, 0.f, 0.f};
    for (int kc = 0; kc < 2; ++kc) {
        if (kc) __syncthreads();
        stage_A_f32(AGG, row0, kc, Ah, Al, tid);
        stage_W(img1 + kc * 8192, img1 + 16384 + kc * 8192, Wh, Wl, tid);
        __syncthreads();
        g_compute(Ah, Al, 0, Wh, Wl, wr, wc, lane, accT);
    }
    __syncthreads();                           // all GEMM1 LDS reads complete

    // ---- T = ssp(accT + b1) -> split bf16 -> Th/Tl; stage W2 chunk 0 ----
    #pragma unroll
    for (int s = 0; s < 2; ++s)
        #pragma unroll
        for (int c = 0; c < 4; ++c) {
            int colg = wc + c * 16 + (lane & 15);
            float bv = b1[colg];
            int kc2 = colg >> 6, kl = colg & 63;
            #pragma unroll
            for (int reg = 0; reg < 4; ++reg) {
                int rl = wr + s * 16 + (lane >> 4) * 4 + reg;     // local row
                float t = ssp_f(accT[s][c][reg] + bv);
                short h, l;
                split_bf16(t, h, l);
                int idx = kc2 * 4096 + rl * 64 + (kl ^ ((rl & 7) << 3));
                Th[idx] = h;
                Tl[idx] = l;
            }
        }
    stage_W(img2, img2 + 16384, Wh, Wl, tid);
    __syncthreads();

    // ---- GEMM2: accV = T @ W2 ----
    fx4 accV[2][4];
    #pragma unroll
    for (int s = 0; s < 2; ++s)
        #pragma unroll
        for (int c = 0; c < 4; ++c)
            accV[s][c] = (fx4){0.f, 0.f, 0.f, 0.f};
    g_compute(Th, Tl, 0, Wh, Wl, wr, wc, lane, accV);
    __syncthreads();
    stage_W(img2 + 8192, img2 + 16384 + 8192, Wh, Wl, tid);
    __syncthreads();
    g_compute(Th, Tl, 4096, Wh, Wl, wr, wc, lane, accV);

    // ---- epilogue: X += accV + b2 ----
    #pragma unroll
    for (int s = 0; s < 2; ++s)
        #pragma unroll
        for (int c = 0; c < 4; ++c) {
            int colg = wc + c * 16 + (lane & 15);
            float bv = b2[colg];
            #pragma unroll
            for (int reg = 0; reg < 4; ++reg) {
                int rowg = row0 + wr + s * 16 + (lane >> 4) * 4 + reg;
                size_t o = (size_t)rowg * NB + colg;
                X[o] += accV[s][c][reg] + bv;
            }
        }
}

extern "C" void kernel_launch(void* const* d_in, const int* in_sizes, int n_in,
                              void* d_out, int out_size, void* d_ws, size_t ws_size,
                              hipStream_t stream) {
    const int*   z    = (const int*)  d_in[0];
    const float* rij  = (const float*)d_in[1];
    const int*   ii   = (const int*)  d_in[2];
    const int*   jj   = (const int*)  d_in[3];
    const float* emb  = (const float*)d_in[4];
    const float* in2f = (const float*)d_in[5];
    const float* fW1  = (const float*)d_in[6];
    const float* fb1  = (const float*)d_in[7];
    const float* fW2  = (const float*)d_in[8];
    const float* fb2  = (const float*)d_in[9];
    const float* oW1  = (const float*)d_in[10];
    const float* ob1  = (const float*)d_in[11];
    const float* oW2  = (const float*)d_in[12];
    const float* ob2  = (const float*)d_in[13];

    const int NXF = N_ATOMS * NB;

    float* X = (float*)d_out;
    unsigned short* HB   = (unsigned short*)d_ws;            // [N_ATOMS][NB] bf16
    float*          AGG  = (float*)(HB + (size_t)NXF);       // [N_ATOMS][NB] fp32
    float*          U    = AGG + (size_t)NXF;                // [N_EDGES] u = d*TSCALE
    unsigned short* TabB = (unsigned short*)(U + N_EDGES);   // [2050][NB] bf16
    short*          Wimg = (short*)(TabB + (size_t)2050 * NB); // 9 x 32768

    k_init<<<I_EMB_BLKS + I_DST_BLKS + 9, 256, 0, stream>>>(z, emb, rij,
                                                            in2f, oW1, oW2,
                                                            X, U, Wimg);

    for (int l = 0; l < NLAYERS; ++l) {
        const short* img_in2f = Wimg + (size_t)(l * 3 + 0) * 32768;
        const short* img_oW1  = Wimg + (size_t)(l * 3 + 1) * 32768;
        const short* img_oW2  = Wimg + (size_t)(l * 3 + 2) * 32768;

        k_pre<<<A_GEMM_BLKS + A_ZERO_BLKS + A_TAB_BLKS, 256, 0, stream>>>(
            X, img_in2f, HB,
            fW1 + (size_t)l * NRBF * NB, fb1 + (size_t)l * NB,
            fW2 + (size_t)l * NB * NB,  fb2 + (size_t)l * NB,
            TabB, AGG);

        k_edge<<<N_EDGES / EPB, 256, 0, stream>>>(U, ii, jj,
                                                  (const unsigned*)HB,
                                                  (const unsigned*)TabB,
                                                  AGG);

        k_outfused<<<N_ATOMS / 64, 256, 0, stream>>>(AGG, img_oW1,
                                                     ob1 + (size_t)l * NB,
                                                     img_oW2,
                                                     ob2 + (size_t)l * NB, X);
    }
}

// Round 7
// 284.361 us; speedup vs baseline: 2.7195x; 1.1413x over previous
//
#include <hip/hip_runtime.h>
#include <math.h>

#define N_ATOMS 40000
#define N_EDGES 640000
#define NB      128
#define NRBF    20
#define NLAYERS 3
#define CUTOFF  5.0f
#define DELTA   (CUTOFF / 19.0f)
#define RBF_COEFF (-0.5f / (DELTA * DELTA))
#define LN2F    0.69314718055994531f

#define KTAB    2048                    // lerp intervals over [0, CUTOFF]
#define TSCALE  ((float)KTAB / CUTOFF)
#define EPB     256                     // edges per block (4 waves x 64)

typedef __attribute__((ext_vector_type(8))) short bf16x8;
typedef __attribute__((ext_vector_type(4))) short bf16x4;
typedef __attribute__((ext_vector_type(4))) float fx4;

__device__ __forceinline__ float ssp_f(float x) {
    return fmaxf(x, 0.f) + __logf(1.f + __expf(-fabsf(x))) - LN2F;
}

__device__ __forceinline__ unsigned short bf16_rne(float x) {
    unsigned u = __float_as_uint(x);
    unsigned r = u + 0x7fffu + ((u >> 16) & 1u);
    return (unsigned short)(r >> 16);
}

__device__ __forceinline__ void split_bf16(float x, short& h, short& l) {
    unsigned u = __float_as_uint(x);
    unsigned r = (u + 0x7fffu + ((u >> 16) & 1u)) & 0xffff0000u;
    h = (short)(r >> 16);
    float lf = x - __uint_as_float(r);
    unsigned u2 = __float_as_uint(lf);
    unsigned r2 = u2 + 0x7fffu + ((u2 >> 16) & 1u);
    l = (short)(r2 >> 16);
}

__device__ __forceinline__ float bfl(unsigned u) { return __uint_as_float(u << 16); }
__device__ __forceinline__ float bfh(unsigned u) { return __uint_as_float(u & 0xffff0000u); }

// ---- shared GEMM building blocks ----

// stage fp32 A-tile chunk (64 rows x 64 k) -> split bf16, swizzled
__device__ __forceinline__ void stage_A_f32(const float* __restrict__ A, int row0, int kc,
                                            short* Ah, short* Al, int tid) {
    #pragma unroll
    for (int it = 0; it < 4; ++it) {
        int idx4 = tid + it * 256;
        int r = idx4 >> 4, kq = (idx4 & 15) << 2;
        float4 v = *(const float4*)(A + (size_t)(row0 + r) * NB + kc * 64 + kq);
        bf16x4 hs, ls;
        const float* vf = (const float*)&v;
        #pragma unroll
        for (int j = 0; j < 4; ++j) {
            short h, l;
            split_bf16(vf[j], h, l);
            hs[j] = h; ls[j] = l;
        }
        int wi = r * 64 + (kq ^ ((r & 7) << 3));
        *(bf16x4*)(Ah + wi) = hs;
        *(bf16x4*)(Al + wi) = ls;
    }
}

// stage A from embedding gather (layer 0): row r of A = emb[z[row0+r]]
__device__ __forceinline__ void stage_A_emb(const float* __restrict__ emb,
                                            const int* __restrict__ z, int row0, int kc,
                                            short* Ah, short* Al, int tid) {
    #pragma unroll
    for (int it = 0; it < 4; ++it) {
        int idx4 = tid + it * 256;
        int r = idx4 >> 4, kq = (idx4 & 15) << 2;
        int zr = z[row0 + r];
        float4 v = *(const float4*)(emb + (size_t)zr * NB + kc * 64 + kq);
        bf16x4 hs, ls;
        const float* vf = (const float*)&v;
        #pragma unroll
        for (int j = 0; j < 4; ++j) {
            short h, l;
            split_bf16(vf[j], h, l);
            hs[j] = h; ls[j] = l;
        }
        int wi = r * 64 + (kq ^ ((r & 7) << 3));
        *(bf16x4*)(Ah + wi) = hs;
        *(bf16x4*)(Al + wi) = ls;
    }
}

// stage pre-swizzled weight chunk image (128 cols x 64 k, hi+lo)
__device__ __forceinline__ void stage_W(const short* __restrict__ imgh,
                                        const short* __restrict__ imgl,
                                        short* Wh, short* Wl, int tid) {
    #pragma unroll
    for (int it = 0; it < 4; ++it) {
        int i = tid + it * 256;
        ((bf16x8*)Wh)[i] = ((const bf16x8*)imgh)[i];
        ((bf16x8*)Wl)[i] = ((const bf16x8*)imgl)[i];
    }
}

// one K=64 chunk of split-bf16 MFMA: acc += A_chunk @ W_chunk
__device__ __forceinline__ void g_compute(const short* AH, const short* AL, int choff,
                                          const short* Wh, const short* Wl,
                                          int wr, int wc, int lane, fx4 acc[2][4]) {
    #pragma unroll
    for (int ks = 0; ks < 2; ++ks) {
        int kb = ks * 32 + (lane >> 4) * 8;
        bf16x8 a_h[2], a_l[2];
        #pragma unroll
        for (int s = 0; s < 2; ++s) {
            int r = wr + s * 16 + (lane & 15);
            int idx = choff + r * 64 + (kb ^ ((r & 7) << 3));
            a_h[s] = *(const bf16x8*)(AH + idx);
            a_l[s] = *(const bf16x8*)(AL + idx);
        }
        #pragma unroll
        for (int c = 0; c < 4; ++c) {
            int col = wc + c * 16 + (lane & 15);
            int idx = col * 64 + (kb ^ ((col & 7) << 3));
            bf16x8 b_h = *(const bf16x8*)(Wh + idx);
            bf16x8 b_l = *(const bf16x8*)(Wl + idx);
            #pragma unroll
            for (int s = 0; s < 2; ++s) {
                acc[s][c] = __builtin_amdgcn_mfma_f32_16x16x32_bf16(a_h[s], b_l, acc[s][c], 0, 0, 0);
                acc[s][c] = __builtin_amdgcn_mfma_f32_16x16x32_bf16(a_l[s], b_h, acc[s][c], 0, 0, 0);
                acc[s][c] = __builtin_amdgcn_mfma_f32_16x16x32_bf16(a_h[s], b_h, acc[s][c], 0, 0, 0);
            }
        }
    }
}

// ---- wide weight prep: 9 weights x 8 segment-blocks ----
__global__ __launch_bounds__(256) void k_wprep(const float* __restrict__ in2f,
                                               const float* __restrict__ oW1,
                                               const float* __restrict__ oW2,
                                               short* __restrict__ Wimg) {
    int b = blockIdx.x, tid = threadIdx.x;
    int w = b >> 3, seg = b & 7;
    int layer = w / 3, which = w % 3;
    const float* W = (which == 0 ? in2f : which == 1 ? oW1 : oW2)
                     + (size_t)layer * NB * NB;
    short* hi = Wimg + (size_t)w * 32768;
    short* lo = hi + 16384;
    int i0 = seg * 2048;
    #pragma unroll
    for (int ofs = 0; ofs < 2048; ofs += 256) {
        int i = i0 + ofs + tid;
        int k = i >> 7, col = i & 127;
        short h, l;
        split_bf16(W[i], h, l);
        int kc = k >> 6, kl = k & 63;
        int idx = kc * 8192 + col * 64 + (kl ^ ((col & 7) << 3));
        hi[idx] = h;
        lo[idx] = l;
    }
}

// ---- fused per-layer pre-edge kernel: GEMM0 + zero AGG + table (+ dist on L0) ----
#define P_GEMM 625
#define P_ZERO 1250
#define P_TAB  1025
#define P_DST  625
template<int L0>
__global__ __launch_bounds__(256) void k_pre(const float* __restrict__ X,
                                             const int* __restrict__ z,
                                             const float* __restrict__ emb,
                                             const float* __restrict__ r_ij,
                                             const short* __restrict__ img0,
                                             unsigned short* __restrict__ HB,
                                             const float* __restrict__ fW1,
                                             const float* __restrict__ fb1,
                                             const float* __restrict__ fW2,
                                             const float* __restrict__ fb2,
                                             unsigned short* __restrict__ TabB,
                                             float* __restrict__ AGG,
                                             float* __restrict__ U) {
    __shared__ short APOOL[24576];               // 48 KB
    int bid = blockIdx.x, tid = threadIdx.x;

    if (bid < P_GEMM) {
        short* Ah = APOOL;
        short* Al = APOOL + 4096;
        short* Wh = APOOL + 8192;
        short* Wl = APOOL + 16384;
        int wave = tid >> 6, lane = tid & 63;
        int wr = (wave & 1) * 32, wc = (wave >> 1) * 64;
        int row0 = bid * 64;
        fx4 acc[2][4];
        #pragma unroll
        for (int s = 0; s < 2; ++s)
            #pragma unroll
            for (int c = 0; c < 4; ++c)
                acc[s][c] = (fx4){0.f, 0.f, 0.f, 0.f};
        for (int kc = 0; kc < 2; ++kc) {
            if (kc) __syncthreads();
            if (L0) stage_A_emb(emb, z, row0, kc, Ah, Al, tid);
            else    stage_A_f32(X, row0, kc, Ah, Al, tid);
            stage_W(img0 + kc * 8192, img0 + 16384 + kc * 8192, Wh, Wl, tid);
            __syncthreads();
            g_compute(Ah, Al, 0, Wh, Wl, wr, wc, lane, acc);
        }
        #pragma unroll
        for (int s = 0; s < 2; ++s)
            #pragma unroll
            for (int c = 0; c < 4; ++c) {
                int colg = wc + c * 16 + (lane & 15);
                #pragma unroll
                for (int reg = 0; reg < 4; ++reg) {
                    int rowg = row0 + wr + s * 16 + (lane >> 4) * 4 + reg;
                    HB[(size_t)rowg * NB + colg] = bf16_rne(acc[s][c][reg]);
                }
            }
    } else if (bid < P_GEMM + P_ZERO) {
        int base = (bid - P_GEMM) * 4096 + tid * 16;
        float4 zv = make_float4(0.f, 0.f, 0.f, 0.f);
        float4* p = (float4*)(AGG + base);
        p[0] = zv; p[1] = zv; p[2] = zv; p[3] = zv;
    } else if (bid < P_GEMM + P_ZERO + P_TAB) {
        int tb = bid - (P_GEMM + P_ZERO);
        int half = tid >> 7, f = tid & 127;
        int r = tb * 2 + half;                    // 0..2049
        if (r >= KTAB) {                          // rows 2048,2049: zero
            TabB[(size_t)r * NB + f] = 0;
            return;
        }
        float* tl = (float*)APOOL;                // 2 x 128 floats
        float d = (float)r * (CUTOFF / (float)KTAB);
        float a = fb1[f];
        #pragma unroll
        for (int q = 0; q < NRBF; ++q) {
            float dr = d - (float)q * DELTA;
            a += __expf(RBF_COEFF * dr * dr) * fW1[q * NB + f];
        }
        tl[half * NB + f] = ssp_f(a);
        __syncthreads();
        float w = fb2[f];
        #pragma unroll 4
        for (int k = 0; k < NB; ++k) w += tl[half * NB + k] * fW2[k * NB + f];
        float rc = 0.5f * (__cosf(d * ((float)M_PI / CUTOFF)) + 1.f);
        TabB[(size_t)r * NB + f] = bf16_rne(w * rc);
    } else if (L0) {
        int e = (bid - (P_GEMM + P_ZERO + P_TAB)) * 1024 + tid * 4;
        const float4* rv = (const float4*)(r_ij + (size_t)e * 3);
        float4 a = rv[0], b = rv[1], c = rv[2];
        float d0 = sqrtf(a.x * a.x + a.y * a.y + a.z * a.z);
        float d1 = sqrtf(a.w * a.w + b.x * b.x + b.y * b.y);
        float d2 = sqrtf(b.z * b.z + b.w * b.w + c.x * c.x);
        float d3 = sqrtf(c.y * c.y + c.z * c.z + c.w * c.w);
        *(float4*)(U + e) = make_float4(d0 * TSCALE, d1 * TSCALE, d2 * TSCALE, d3 * TSCALE);
    }
}

// ---- edge kernel: 2 independent 32-edge sub-streams per wave for 2x gather MLP ----
__global__ __launch_bounds__(256) void k_edge(const float* __restrict__ U,
                                              const int* __restrict__ idx_i,
                                              const int* __restrict__ idx_j,
                                              const unsigned* __restrict__ HBv,
                                              const unsigned* __restrict__ TabU,
                                              float* __restrict__ AGG) {
    __shared__ float u_s[EPB];
    __shared__ int   i_s[EPB];
    __shared__ int   j_s[EPB];
    int tid = threadIdx.x;
    int e0 = blockIdx.x * EPB;
    u_s[tid] = U[e0 + tid];
    i_s[tid] = idx_i[e0 + tid];
    j_s[tid] = idx_j[e0 + tid];
    __syncthreads();

    int wave = tid >> 6, lane = tid & 63;
    int wbase = wave << 6;

    float axA = 0.f, ayA = 0.f, axB = 0.f, ayB = 0.f;
    int curA = -1, curB = -1;
    int nfA = 0, nfB = 0;

    #pragma unroll 2
    for (int t = 0; t < 32; ++t) {
        int eA = wbase + t;
        int eB = wbase + 32 + t;
        float uA = u_s[eA], uB = u_s[eB];
        int   iaA = i_s[eA], iaB = i_s[eB];
        int   jaA = j_s[eA], jaB = j_s[eB];

        int kA = (int)uA; kA = (kA > KTAB) ? KTAB : kA;
        int kB = (int)uB; kB = (kB > KTAB) ? KTAB : kB;
        float frA = uA - (float)kA;
        float frB = uB - (float)kB;

        unsigned v0A = TabU[(size_t)kA * 64 + lane];
        unsigned v1A = TabU[(size_t)kA * 64 + 64 + lane];
        unsigned v0B = TabU[(size_t)kB * 64 + lane];
        unsigned v1B = TabU[(size_t)kB * 64 + 64 + lane];
        unsigned hqA = HBv[(size_t)jaA * 64 + lane];
        unsigned hqB = HBv[(size_t)jaB * 64 + lane];

        float w0A = fmaf(frA, bfl(v1A) - bfl(v0A), bfl(v0A));
        float w1A = fmaf(frA, bfh(v1A) - bfh(v0A), bfh(v0A));
        float w0B = fmaf(frB, bfl(v1B) - bfl(v0B), bfl(v0B));
        float w1B = fmaf(frB, bfh(v1B) - bfh(v0B), bfh(v0B));

        if (iaA != curA) {                     // wave-uniform
            if (curA >= 0) {
                float* p = AGG + (size_t)curA * NB + 2 * lane;
                if (nfA == 0) { atomicAdd(p, axA); atomicAdd(p + 1, ayA); }
                else          { *(float2*)p = make_float2(axA, ayA); }
                ++nfA;
            }
            axA = 0.f; ayA = 0.f;
            curA = iaA;
        }
        axA = fmaf(bfl(hqA), w0A, axA);
        ayA = fmaf(bfh(hqA), w1A, ayA);

        if (iaB != curB) {                     // wave-uniform
            if (curB >= 0) {
                float* p = AGG + (size_t)curB * NB + 2 * lane;
                if (nfB == 0) { atomicAdd(p, axB); atomicAdd(p + 1, ayB); }
                else          { *(float2*)p = make_float2(axB, ayB); }
                ++nfB;
            }
            axB = 0.f; ayB = 0.f;
            curB = iaB;
        }
        axB = fmaf(bfl(hqB), w0B, axB);
        ayB = fmaf(bfh(hqB), w1B, ayB);
    }
    if (curA >= 0) {                           // final flushes: always atomic
        float* p = AGG + (size_t)curA * NB + 2 * lane;
        atomicAdd(p, axA); atomicAdd(p + 1, ayA);
    }
    if (curB >= 0) {
        float* p = AGG + (size_t)curB * NB + 2 * lane;
        atomicAdd(p, axB); atomicAdd(p + 1, ayB);
    }
}

// ---- fused out-MLP: X (+)= ssp(AGG@W1+b1)@W2 + b2, T kept in LDS ----
// L0: X = emb[z] + v + b2  (embedding residual folded in, no X read)
template<int L0>
__global__ __launch_bounds__(256) void k_outfused(const float* __restrict__ AGG,
                                                  const short* __restrict__ img1,
                                                  const float* __restrict__ b1,
                                                  const short* __restrict__ img2,
                                                  const float* __restrict__ b2,
                                                  const int* __restrict__ z,
                                                  const float* __restrict__ emb,
                                                  float* __restrict__ X) {
    __shared__ short POOL[32768];              // 64 KB
    short* Ah = POOL;
    short* Al = POOL + 4096;
    short* Th = POOL;                          // overlays A after GEMM1
    short* Tl = POOL + 8192;
    short* Wh = POOL + 16384;
    short* Wl = POOL + 24576;

    int tid = threadIdx.x;
    int wave = tid >> 6, lane = tid & 63;
    int wr = (wave & 1) * 32, wc = (wave >> 1) * 64;
    int row0 = blockIdx.x * 64;

    fx4 accT[2][4];
    #pragma unroll
    for (int s = 0; s < 2; ++s)
        #pragma unroll
        for (int c = 0; c < 4; ++c)
            accT[s][c] = (fx4){0.f, 0.f, 0.f, 0.f};
    for (int kc = 0; kc < 2; ++kc) {
        if (kc) __syncthreads();
        stage_A_f32(AGG, row0, kc, Ah, Al, tid);
        stage_W(img1 + kc * 8192, img1 + 16384 + kc * 8192, Wh, Wl, tid);
        __syncthreads();
        g_compute(Ah, Al, 0, Wh, Wl, wr, wc, lane, accT);
    }
    __syncthreads();

    #pragma unroll
    for (int s = 0; s < 2; ++s)
        #pragma unroll
        for (int c = 0; c < 4; ++c) {
            int colg = wc + c * 16 + (lane & 15);
            float bv = b1[colg];
            int kc2 = colg >> 6, kl = colg & 63;
            #pragma unroll
            for (int reg = 0; reg < 4; ++reg) {
                int rl = wr + s * 16 + (lane >> 4) * 4 + reg;
                float t = ssp_f(accT[s][c][reg] + bv);
                short h, l;
                split_bf16(t, h, l);
                int idx = kc2 * 4096 + rl * 64 + (kl ^ ((rl & 7) << 3));
                Th[idx] = h;
                Tl[idx] = l;
            }
        }
    stage_W(img2, img2 + 16384, Wh, Wl, tid);
    __syncthreads();

    fx4 accV[2][4];
    #pragma unroll
    for (int s = 0; s < 2; ++s)
        #pragma unroll
        for (int c = 0; c < 4; ++c)
            accV[s][c] = (fx4){0.f, 0.f, 0.f, 0.f};
    g_compute(Th, Tl, 0, Wh, Wl, wr, wc, lane, accV);
    __syncthreads();
    stage_W(img2 + 8192, img2 + 16384 + 8192, Wh, Wl, tid);
    __syncthreads();
    g_compute(Th, Tl, 4096, Wh, Wl, wr, wc, lane, accV);

    #pragma unroll
    for (int s = 0; s < 2; ++s)
        #pragma unroll
        for (int c = 0; c < 4; ++c) {
            int colg = wc + c * 16 + (lane & 15);
            float bv = b2[colg];
            #pragma unroll
            for (int reg = 0; reg < 4; ++reg) {
                int rowg = row0 + wr + s * 16 + (lane >> 4) * 4 + reg;
                size_t o = (size_t)rowg * NB + colg;
                if (L0) {
                    int zr = z[rowg];
                    X[o] = emb[(size_t)zr * NB + colg] + accV[s][c][reg] + bv;
                } else {
                    X[o] += accV[s][c][reg] + bv;
                }
            }
        }
}

extern "C" void kernel_launch(void* const* d_in, const int* in_sizes, int n_in,
                              void* d_out, int out_size, void* d_ws, size_t ws_size,
                              hipStream_t stream) {
    const int*   z    = (const int*)  d_in[0];
    const float* rij  = (const float*)d_in[1];
    const int*   ii   = (const int*)  d_in[2];
    const int*   jj   = (const int*)  d_in[3];
    const float* emb  = (const float*)d_in[4];
    const float* in2f = (const float*)d_in[5];
    const float* fW1  = (const float*)d_in[6];
    const float* fb1  = (const float*)d_in[7];
    const float* fW2  = (const float*)d_in[8];
    const float* fb2  = (const float*)d_in[9];
    const float* oW1  = (const float*)d_in[10];
    const float* ob1  = (const float*)d_in[11];
    const float* oW2  = (const float*)d_in[12];
    const float* ob2  = (const float*)d_in[13];

    const int NXF = N_ATOMS * NB;

    float* X = (float*)d_out;
    unsigned short* HB   = (unsigned short*)d_ws;              // [N_ATOMS][NB] bf16
    float*          AGG  = (float*)(HB + (size_t)NXF);         // [N_ATOMS][NB] fp32
    float*          U    = AGG + (size_t)NXF;                  // [N_EDGES] u = d*TSCALE
    unsigned short* TabB = (unsigned short*)(U + N_EDGES);     // [2050][NB] bf16
    short*          Wimg = (short*)(TabB + (size_t)2050 * NB); // 9 x 32768

    k_wprep<<<72, 256, 0, stream>>>(in2f, oW1, oW2, Wimg);

    for (int l = 0; l < NLAYERS; ++l) {
        const short* img_in2f = Wimg + (size_t)(l * 3 + 0) * 32768;
        const short* img_oW1  = Wimg + (size_t)(l * 3 + 1) * 32768;
        const short* img_oW2  = Wimg + (size_t)(l * 3 + 2) * 32768;
        const float* w1 = fW1 + (size_t)l * NRBF * NB;
        const float* bb1 = fb1 + (size_t)l * NB;
        const float* w2 = fW2 + (size_t)l * NB * NB;
        const float* bb2 = fb2 + (size_t)l * NB;

        if (l == 0)
            k_pre<1><<<P_GEMM + P_ZERO + P_TAB + P_DST, 256, 0, stream>>>(
                X, z, emb, rij, img_in2f, HB, w1, bb1, w2, bb2, TabB, AGG, U);
        else
            k_pre<0><<<P_GEMM + P_ZERO + P_TAB, 256, 0, stream>>>(
                X, z, emb, rij, img_in2f, HB, w1, bb1, w2, bb2, TabB, AGG, U);

        k_edge<<<N_EDGES / EPB, 256, 0, stream>>>(U, ii, jj,
                                                  (const unsigned*)HB,
                                                  (const unsigned*)TabB,
                                                  AGG);

        if (l == 0)
            k_outfused<1><<<N_ATOMS / 64, 256, 0, stream>>>(AGG, img_oW1,
                                                            ob1 + (size_t)l * NB,
                                                            img_oW2,
                                                            ob2 + (size_t)l * NB,
                                                            z, emb, X);
        else
            k_outfused<0><<<N_ATOMS / 64, 256, 0, stream>>>(AGG, img_oW1,
                                                            ob1 + (size_t)l * NB,
                                                            img_oW2,
                                                            ob2 + (size_t)l * NB,
                                                            z, emb, X);
    }
}

// Round 8
// 255.286 us; speedup vs baseline: 3.0292x; 1.1139x over previous
//
#include <hip/hip_runtime.h>
#include <math.h>

#define N_ATOMS 40000
#define N_EDGES 640000
#define NB      128
#define NRBF    20
#define NLAYERS 3
#define CUTOFF  5.0f
#define DELTA   (CUTOFF / 19.0f)
#define RBF_COEFF (-0.5f / (DELTA * DELTA))
#define LN2F    0.69314718055994531f

#define KTAB    2048
#define TSCALE  ((float)KTAB / CUTOFF)
#define EPB     256
#define EBLKS   (N_EDGES / EPB)         // 2500
#define TABBLKS 1025                    // rows 0..2049, 2 per block

typedef __attribute__((ext_vector_type(8))) short bf16x8;
typedef __attribute__((ext_vector_type(4))) short bf16x4;
typedef __attribute__((ext_vector_type(4))) float fx4;

__device__ __forceinline__ float ssp_f(float x) {
    return fmaxf(x, 0.f) + __logf(1.f + __expf(-fabsf(x))) - LN2F;
}

__device__ __forceinline__ unsigned short bf16_rne(float x) {
    unsigned u = __float_as_uint(x);
    unsigned r = u + 0x7fffu + ((u >> 16) & 1u);
    return (unsigned short)(r >> 16);
}

__device__ __forceinline__ void split_bf16(float x, short& h, short& l) {
    unsigned u = __float_as_uint(x);
    unsigned r = (u + 0x7fffu + ((u >> 16) & 1u)) & 0xffff0000u;
    h = (short)(r >> 16);
    float lf = x - __uint_as_float(r);
    unsigned u2 = __float_as_uint(lf);
    unsigned r2 = u2 + 0x7fffu + ((u2 >> 16) & 1u);
    l = (short)(r2 >> 16);
}

__device__ __forceinline__ float bfl(unsigned u) { return __uint_as_float(u << 16); }
__device__ __forceinline__ float bfh(unsigned u) { return __uint_as_float(u & 0xffff0000u); }

// ---- GEMM building blocks ----

__device__ __forceinline__ void stage_A_f32(const float* __restrict__ A, int row0, int kc,
                                            short* Ah, short* Al, int tid) {
    #pragma unroll
    for (int it = 0; it < 4; ++it) {
        int idx4 = tid + it * 256;
        int r = idx4 >> 4, kq = (idx4 & 15) << 2;
        float4 v = *(const float4*)(A + (size_t)(row0 + r) * NB + kc * 64 + kq);
        bf16x4 hs, ls;
        const float* vf = (const float*)&v;
        #pragma unroll
        for (int j = 0; j < 4; ++j) {
            short h, l;
            split_bf16(vf[j], h, l);
            hs[j] = h; ls[j] = l;
        }
        int wi = r * 64 + (kq ^ ((r & 7) << 3));
        *(bf16x4*)(Ah + wi) = hs;
        *(bf16x4*)(Al + wi) = ls;
    }
}

// stage AGG chunk and zero it behind the read (next-layer prep)
template<int ZERO>
__device__ __forceinline__ void stage_A_agg(float* __restrict__ A, int row0, int kc,
                                            short* Ah, short* Al, int tid) {
    #pragma unroll
    for (int it = 0; it < 4; ++it) {
        int idx4 = tid + it * 256;
        int r = idx4 >> 4, kq = (idx4 & 15) << 2;
        float* src = A + (size_t)(row0 + r) * NB + kc * 64 + kq;
        float4 v = *(const float4*)src;
        if (ZERO) *(float4*)src = make_float4(0.f, 0.f, 0.f, 0.f);
        bf16x4 hs, ls;
        const float* vf = (const float*)&v;
        #pragma unroll
        for (int j = 0; j < 4; ++j) {
            short h, l;
            split_bf16(vf[j], h, l);
            hs[j] = h; ls[j] = l;
        }
        int wi = r * 64 + (kq ^ ((r & 7) << 3));
        *(bf16x4*)(Ah + wi) = hs;
        *(bf16x4*)(Al + wi) = ls;
    }
}

// stage A from embedding gather (layer 0 GEMM0)
__device__ __forceinline__ void stage_A_emb(const float* __restrict__ emb,
                                            const int* __restrict__ z, int row0, int kc,
                                            short* Ah, short* Al, int tid) {
    #pragma unroll
    for (int it = 0; it < 4; ++it) {
        int idx4 = tid + it * 256;
        int r = idx4 >> 4, kq = (idx4 & 15) << 2;
        int zr = z[row0 + r];
        float4 v = *(const float4*)(emb + (size_t)zr * NB + kc * 64 + kq);
        bf16x4 hs, ls;
        const float* vf = (const float*)&v;
        #pragma unroll
        for (int j = 0; j < 4; ++j) {
            short h, l;
            split_bf16(vf[j], h, l);
            hs[j] = h; ls[j] = l;
        }
        int wi = r * 64 + (kq ^ ((r & 7) << 3));
        *(bf16x4*)(Ah + wi) = hs;
        *(bf16x4*)(Al + wi) = ls;
    }
}

__device__ __forceinline__ void stage_W(const short* __restrict__ imgh,
                                        const short* __restrict__ imgl,
                                        short* Wh, short* Wl, int tid) {
    #pragma unroll
    for (int it = 0; it < 4; ++it) {
        int i = tid + it * 256;
        ((bf16x8*)Wh)[i] = ((const bf16x8*)imgh)[i];
        ((bf16x8*)Wl)[i] = ((const bf16x8*)imgl)[i];
    }
}

// stage W chunk directly from fp32 W[k][col] (layer-0 GEMM0 only; no image)
__device__ __forceinline__ void stage_W_f32(const float* __restrict__ W, int kc,
                                            short* Wh, short* Wl, int tid) {
    #pragma unroll
    for (int it = 0; it < 8; ++it) {
        int i = tid + it * 256;            // 0..2047
        int kl = i >> 5;                   // 0..63
        int c0 = (i & 31) << 2;            // col base
        float4 v = *(const float4*)(W + (size_t)(kc * 64 + kl) * NB + c0);
        const float* vf = (const float*)&v;
        #pragma unroll
        for (int j = 0; j < 4; ++j) {
            short h, l;
            split_bf16(vf[j], h, l);
            int col = c0 + j;
            int idx = col * 64 + (kl ^ ((col & 7) << 3));
            Wh[idx] = h;
            Wl[idx] = l;
        }
    }
}

__device__ __forceinline__ void g_compute(const short* AH, const short* AL, int choff,
                                          const short* Wh, const short* Wl,
                                          int wr, int wc, int lane, fx4 acc[2][4]) {
    #pragma unroll
    for (int ks = 0; ks < 2; ++ks) {
        int kb = ks * 32 + (lane >> 4) * 8;
        bf16x8 a_h[2], a_l[2];
        #pragma unroll
        for (int s = 0; s < 2; ++s) {
            int r = wr + s * 16 + (lane & 15);
            int idx = choff + r * 64 + (kb ^ ((r & 7) << 3));
            a_h[s] = *(const bf16x8*)(AH + idx);
            a_l[s] = *(const bf16x8*)(AL + idx);
        }
        #pragma unroll
        for (int c = 0; c < 4; ++c) {
            int col = wc + c * 16 + (lane & 15);
            int idx = col * 64 + (kb ^ ((col & 7) << 3));
            bf16x8 b_h = *(const bf16x8*)(Wh + idx);
            bf16x8 b_l = *(const bf16x8*)(Wl + idx);
            #pragma unroll
            for (int s = 0; s < 2; ++s) {
                acc[s][c] = __builtin_amdgcn_mfma_f32_16x16x32_bf16(a_h[s], b_l, acc[s][c], 0, 0, 0);
                acc[s][c] = __builtin_amdgcn_mfma_f32_16x16x32_bf16(a_l[s], b_h, acc[s][c], 0, 0, 0);
                acc[s][c] = __builtin_amdgcn_mfma_f32_16x16x32_bf16(a_h[s], b_h, acc[s][c], 0, 0, 0);
            }
        }
    }
}

// ---- k_pre0: layer-0 GEMM0 (direct W stage) + zero AGG + table0 + dist + wprep(w=1..8) ----
#define P0_GEMM 625
#define P0_ZERO 1250
#define P0_TAB  1025
#define P0_DST  625
#define P0_WPR  64
__global__ __launch_bounds__(256) void k_pre0(const int* __restrict__ z,
                                              const float* __restrict__ emb,
                                              const float* __restrict__ r_ij,
                                              const float* __restrict__ in2f,
                                              const float* __restrict__ oW1,
                                              const float* __restrict__ oW2,
                                              const float* __restrict__ fW1,
                                              const float* __restrict__ fb1,
                                              const float* __restrict__ fW2,
                                              const float* __restrict__ fb2,
                                              unsigned short* __restrict__ HB,
                                              unsigned short* __restrict__ TabB,
                                              float* __restrict__ AGG,
                                              float* __restrict__ U,
                                              short* __restrict__ Wimg) {
    __shared__ short APOOL[24576];               // 48 KB
    int bid = blockIdx.x, tid = threadIdx.x;

    if (bid < P0_GEMM) {
        short* Ah = APOOL;
        short* Al = APOOL + 4096;
        short* Wh = APOOL + 8192;
        short* Wl = APOOL + 16384;
        int wave = tid >> 6, lane = tid & 63;
        int wr = (wave & 1) * 32, wc = (wave >> 1) * 64;
        int row0 = bid * 64;
        fx4 acc[2][4];
        #pragma unroll
        for (int s = 0; s < 2; ++s)
            #pragma unroll
            for (int c = 0; c < 4; ++c)
                acc[s][c] = (fx4){0.f, 0.f, 0.f, 0.f};
        for (int kc = 0; kc < 2; ++kc) {
            if (kc) __syncthreads();
            stage_A_emb(emb, z, row0, kc, Ah, Al, tid);
            stage_W_f32(in2f, kc, Wh, Wl, tid);
            __syncthreads();
            g_compute(Ah, Al, 0, Wh, Wl, wr, wc, lane, acc);
        }
        #pragma unroll
        for (int s = 0; s < 2; ++s)
            #pragma unroll
            for (int c = 0; c < 4; ++c) {
                int colg = wc + c * 16 + (lane & 15);
                #pragma unroll
                for (int reg = 0; reg < 4; ++reg) {
                    int rowg = row0 + wr + s * 16 + (lane >> 4) * 4 + reg;
                    HB[(size_t)rowg * NB + colg] = bf16_rne(acc[s][c][reg]);
                }
            }
    } else if (bid < P0_GEMM + P0_ZERO) {
        int base = (bid - P0_GEMM) * 4096 + tid * 16;
        float4 zv = make_float4(0.f, 0.f, 0.f, 0.f);
        float4* p = (float4*)(AGG + base);
        p[0] = zv; p[1] = zv; p[2] = zv; p[3] = zv;
    } else if (bid < P0_GEMM + P0_ZERO + P0_TAB) {
        int tb = bid - (P0_GEMM + P0_ZERO);
        int half = tid >> 7, f = tid & 127;
        int r = tb * 2 + half;
        if (r >= KTAB) {
            TabB[(size_t)r * NB + f] = 0;
            return;
        }
        float* tl = (float*)APOOL;
        float d = (float)r * (CUTOFF / (float)KTAB);
        float a = fb1[f];
        #pragma unroll
        for (int q = 0; q < NRBF; ++q) {
            float dr = d - (float)q * DELTA;
            a += __expf(RBF_COEFF * dr * dr) * fW1[q * NB + f];
        }
        tl[half * NB + f] = ssp_f(a);
        __syncthreads();
        float w = fb2[f];
        #pragma unroll 4
        for (int k = 0; k < NB; ++k) w += tl[half * NB + k] * fW2[k * NB + f];
        float rc = 0.5f * (__cosf(d * ((float)M_PI / CUTOFF)) + 1.f);
        TabB[(size_t)r * NB + f] = bf16_rne(w * rc);
    } else if (bid < P0_GEMM + P0_ZERO + P0_TAB + P0_DST) {
        int e = (bid - (P0_GEMM + P0_ZERO + P0_TAB)) * 1024 + tid * 4;
        const float4* rv = (const float4*)(r_ij + (size_t)e * 3);
        float4 a = rv[0], b = rv[1], c = rv[2];
        float d0 = sqrtf(a.x * a.x + a.y * a.y + a.z * a.z);
        float d1 = sqrtf(a.w * a.w + b.x * b.x + b.y * b.y);
        float d2 = sqrtf(b.z * b.z + b.w * b.w + c.x * c.x);
        float d3 = sqrtf(c.y * c.y + c.z * c.z + c.w * c.w);
        *(float4*)(U + e) = make_float4(d0 * TSCALE, d1 * TSCALE, d2 * TSCALE, d3 * TSCALE);
    } else {
        int b2 = bid - (P0_GEMM + P0_ZERO + P0_TAB + P0_DST);   // 0..63
        int w = 1 + (b2 >> 3), seg = b2 & 7;                    // images 1..8
        int layer = w / 3, which = w % 3;
        const float* W = (which == 0 ? in2f : which == 1 ? oW1 : oW2)
                         + (size_t)layer * NB * NB;
        short* hi = Wimg + (size_t)w * 32768;
        short* lo = hi + 16384;
        int i0 = seg * 2048;
        #pragma unroll
        for (int ofs = 0; ofs < 2048; ofs += 256) {
            int i = i0 + ofs + tid;
            int k = i >> 7, col = i & 127;
            short h, l;
            split_bf16(W[i], h, l);
            int kc = k >> 6, kl = k & 63;
            int idx = kc * 8192 + col * 64 + (kl ^ ((col & 7) << 3));
            hi[idx] = h;
            lo[idx] = l;
        }
    }
}

// ---- edge kernel (R7 dual-stream) + appended next-layer table blocks ----
__global__ __launch_bounds__(256) void k_edge(const float* __restrict__ U,
                                              const int* __restrict__ idx_i,
                                              const int* __restrict__ idx_j,
                                              const unsigned* __restrict__ HBv,
                                              const unsigned* __restrict__ TabU,
                                              float* __restrict__ AGG,
                                              const float* __restrict__ nW1,
                                              const float* __restrict__ nb1,
                                              const float* __restrict__ nW2,
                                              const float* __restrict__ nb2,
                                              unsigned short* __restrict__ TabN) {
    __shared__ float u_s[EPB];
    __shared__ int   i_s[EPB];
    __shared__ int   j_s[EPB];
    __shared__ float t_lds[256];
    int tid = threadIdx.x;
    int bid = blockIdx.x;

    if (bid >= EBLKS) {                        // next-layer table block
        int tb = bid - EBLKS;
        int half = tid >> 7, f = tid & 127;
        int r = tb * 2 + half;
        if (r >= KTAB) {
            TabN[(size_t)r * NB + f] = 0;
            return;
        }
        float d = (float)r * (CUTOFF / (float)KTAB);
        float a = nb1[f];
        #pragma unroll
        for (int q = 0; q < NRBF; ++q) {
            float dr = d - (float)q * DELTA;
            a += __expf(RBF_COEFF * dr * dr) * nW1[q * NB + f];
        }
        t_lds[half * NB + f] = ssp_f(a);
        __syncthreads();
        float w = nb2[f];
        #pragma unroll 4
        for (int k = 0; k < NB; ++k) w += t_lds[half * NB + k] * nW2[k * NB + f];
        float rc = 0.5f * (__cosf(d * ((float)M_PI / CUTOFF)) + 1.f);
        TabN[(size_t)r * NB + f] = bf16_rne(w * rc);
        return;
    }

    int e0 = bid * EPB;
    u_s[tid] = U[e0 + tid];
    i_s[tid] = idx_i[e0 + tid];
    j_s[tid] = idx_j[e0 + tid];
    __syncthreads();

    int wave = tid >> 6, lane = tid & 63;
    int wbase = wave << 6;

    float axA = 0.f, ayA = 0.f, axB = 0.f, ayB = 0.f;
    int curA = -1, curB = -1;
    int nfA = 0, nfB = 0;

    #pragma unroll 2
    for (int t = 0; t < 32; ++t) {
        int eA = wbase + t;
        int eB = wbase + 32 + t;
        float uA = u_s[eA], uB = u_s[eB];
        int   iaA = i_s[eA], iaB = i_s[eB];
        int   jaA = j_s[eA], jaB = j_s[eB];

        int kA = (int)uA; kA = (kA > KTAB) ? KTAB : kA;
        int kB = (int)uB; kB = (kB > KTAB) ? KTAB : kB;
        float frA = uA - (float)kA;
        float frB = uB - (float)kB;

        unsigned v0A = TabU[(size_t)kA * 64 + lane];
        unsigned v1A = TabU[(size_t)kA * 64 + 64 + lane];
        unsigned v0B = TabU[(size_t)kB * 64 + lane];
        unsigned v1B = TabU[(size_t)kB * 64 + 64 + lane];
        unsigned hqA = HBv[(size_t)jaA * 64 + lane];
        unsigned hqB = HBv[(size_t)jaB * 64 + lane];

        float w0A = fmaf(frA, bfl(v1A) - bfl(v0A), bfl(v0A));
        float w1A = fmaf(frA, bfh(v1A) - bfh(v0A), bfh(v0A));
        float w0B = fmaf(frB, bfl(v1B) - bfl(v0B), bfl(v0B));
        float w1B = fmaf(frB, bfh(v1B) - bfh(v0B), bfh(v0B));

        if (iaA != curA) {
            if (curA >= 0) {
                float* p = AGG + (size_t)curA * NB + 2 * lane;
                if (nfA == 0) { atomicAdd(p, axA); atomicAdd(p + 1, ayA); }
                else          { *(float2*)p = make_float2(axA, ayA); }
                ++nfA;
            }
            axA = 0.f; ayA = 0.f;
            curA = iaA;
        }
        axA = fmaf(bfl(hqA), w0A, axA);
        ayA = fmaf(bfh(hqA), w1A, ayA);

        if (iaB != curB) {
            if (curB >= 0) {
                float* p = AGG + (size_t)curB * NB + 2 * lane;
                if (nfB == 0) { atomicAdd(p, axB); atomicAdd(p + 1, ayB); }
                else          { *(float2*)p = make_float2(axB, ayB); }
                ++nfB;
            }
            axB = 0.f; ayB = 0.f;
            curB = iaB;
        }
        axB = fmaf(bfl(hqB), w0B, axB);
        ayB = fmaf(bfh(hqB), w1B, ayB);
    }
    if (curA >= 0) {
        float* p = AGG + (size_t)curA * NB + 2 * lane;
        atomicAdd(p, axA); atomicAdd(p + 1, ayA);
    }
    if (curB >= 0) {
        float* p = AGG + (size_t)curB * NB + 2 * lane;
        atomicAdd(p, axB); atomicAdd(p + 1, ayB);
    }
}

// ---- k_fuse: X (+)= ssp(AGG@W1+b1)@W2+b2, zero AGG behind read,
//      then HB = bf16(X_new @ in2f_next) without re-reading X ----
template<int FIRST, int LAST>
__global__ __launch_bounds__(256) void k_fuse(float* __restrict__ AGG,
                                              const short* __restrict__ img1,
                                              const float* __restrict__ b1,
                                              const short* __restrict__ img2,
                                              const float* __restrict__ b2,
                                              const short* __restrict__ img0n,
                                              const int* __restrict__ z,
                                              const float* __restrict__ emb,
                                              float* __restrict__ X,
                                              unsigned short* __restrict__ HB) {
    __shared__ short POOL[32768];              // 64 KB
    short* Ah = POOL;                          // GEMM1 A chunk
    short* Al = POOL + 4096;
    short* Th = POOL;                          // T / X_new hi (2 chunks x 4096)
    short* Tl = POOL + 8192;                   // T / X_new lo
    short* Wh = POOL + 16384;
    short* Wl = POOL + 24576;

    int tid = threadIdx.x;
    int wave = tid >> 6, lane = tid & 63;
    int wr = (wave & 1) * 32, wc = (wave >> 1) * 64;
    int row0 = blockIdx.x * 64;

    // GEMM1: accT = AGG @ W1 (+ zero AGG behind the read unless LAST)
    fx4 accT[2][4];
    #pragma unroll
    for (int s = 0; s < 2; ++s)
        #pragma unroll
        for (int c = 0; c < 4; ++c)
            accT[s][c] = (fx4){0.f, 0.f, 0.f, 0.f};
    for (int kc = 0; kc < 2; ++kc) {
        if (kc) __syncthreads();
        stage_A_agg<!LAST>(AGG, row0, kc, Ah, Al, tid);
        stage_W(img1 + kc * 8192, img1 + 16384 + kc * 8192, Wh, Wl, tid);
        __syncthreads();
        g_compute(Ah, Al, 0, Wh, Wl, wr, wc, lane, accT);
    }
    __syncthreads();

    // T = ssp(accT + b1) -> LDS split-bf16
    #pragma unroll
    for (int s = 0; s < 2; ++s)
        #pragma unroll
        for (int c = 0; c < 4; ++c) {
            int colg = wc + c * 16 + (lane & 15);
            float bv = b1[colg];
            int kc2 = colg >> 6, kl = colg & 63;
            #pragma unroll
            for (int reg = 0; reg < 4; ++reg) {
                int rl = wr + s * 16 + (lane >> 4) * 4 + reg;
                float t = ssp_f(accT[s][c][reg] + bv);
                short h, l;
                split_bf16(t, h, l);
                int idx = kc2 * 4096 + rl * 64 + (kl ^ ((rl & 7) << 3));
                Th[idx] = h;
                Tl[idx] = l;
            }
        }
    stage_W(img2, img2 + 16384, Wh, Wl, tid);
    __syncthreads();

    // GEMM2: accV = T @ W2
    fx4 accV[2][4];
    #pragma unroll
    for (int s = 0; s < 2; ++s)
        #pragma unroll
        for (int c = 0; c < 4; ++c)
            accV[s][c] = (fx4){0.f, 0.f, 0.f, 0.f};
    g_compute(Th, Tl, 0, Wh, Wl, wr, wc, lane, accV);
    __syncthreads();
    stage_W(img2 + 8192, img2 + 16384 + 8192, Wh, Wl, tid);
    __syncthreads();
    g_compute(Th, Tl, 4096, Wh, Wl, wr, wc, lane, accV);
    __syncthreads();                           // T dead; region reusable for X_new

    // epilogue: X_new = X_old + accV + b2; write X; stage X_new for GEMM3
    #pragma unroll
    for (int s = 0; s < 2; ++s)
        #pragma unroll
        for (int c = 0; c < 4; ++c) {
            int colg = wc + c * 16 + (lane & 15);
            float bv = b2[colg];
            int kc2 = colg >> 6, kl = colg & 63;
            #pragma unroll
            for (int reg = 0; reg < 4; ++reg) {
                int rowg = row0 + wr + s * 16 + (lane >> 4) * 4 + reg;
                size_t o = (size_t)rowg * NB + colg;
                float xo;
                if (FIRST) xo = emb[(size_t)z[rowg] * NB + colg];
                else       xo = X[o];
                float xn = xo + accV[s][c][reg] + bv;
                X[o] = xn;
                if (!LAST) {
                    int rl = wr + s * 16 + (lane >> 4) * 4 + reg;
                    short h, l;
                    split_bf16(xn, h, l);
                    int idx = kc2 * 4096 + rl * 64 + (kl ^ ((rl & 7) << 3));
                    Th[idx] = h;
                    Tl[idx] = l;
                }
            }
        }
    if (LAST) return;

    // GEMM3: HB = bf16(X_new @ in2f_next)
    stage_W(img0n, img0n + 16384, Wh, Wl, tid);
    __syncthreads();
    fx4 accH[2][4];
    #pragma unroll
    for (int s = 0; s < 2; ++s)
        #pragma unroll
        for (int c = 0; c < 4; ++c)
            accH[s][c] = (fx4){0.f, 0.f, 0.f, 0.f};
    g_compute(Th, Tl, 0, Wh, Wl, wr, wc, lane, accH);
    __syncthreads();
    stage_W(img0n + 8192, img0n + 16384 + 8192, Wh, Wl, tid);
    __syncthreads();
    g_compute(Th, Tl, 4096, Wh, Wl, wr, wc, lane, accH);

    #pragma unroll
    for (int s = 0; s < 2; ++s)
        #pragma unroll
        for (int c = 0; c < 4; ++c) {
            int colg = wc + c * 16 + (lane & 15);
            #pragma unroll
            for (int reg = 0; reg < 4; ++reg) {
                int rowg = row0 + wr + s * 16 + (lane >> 4) * 4 + reg;
                HB[(size_t)rowg * NB + colg] = bf16_rne(accH[s][c][reg]);
            }
        }
}

extern "C" void kernel_launch(void* const* d_in, const int* in_sizes, int n_in,
                              void* d_out, int out_size, void* d_ws, size_t ws_size,
                              hipStream_t stream) {
    const int*   z    = (const int*)  d_in[0];
    const float* rij  = (const float*)d_in[1];
    const int*   ii   = (const int*)  d_in[2];
    const int*   jj   = (const int*)  d_in[3];
    const float* emb  = (const float*)d_in[4];
    const float* in2f = (const float*)d_in[5];
    const float* fW1  = (const float*)d_in[6];
    const float* fb1  = (const float*)d_in[7];
    const float* fW2  = (const float*)d_in[8];
    const float* fb2  = (const float*)d_in[9];
    const float* oW1  = (const float*)d_in[10];
    const float* ob1  = (const float*)d_in[11];
    const float* oW2  = (const float*)d_in[12];
    const float* ob2  = (const float*)d_in[13];

    const int NXF = N_ATOMS * NB;

    float* X = (float*)d_out;
    unsigned short* HB   = (unsigned short*)d_ws;              // [N_ATOMS][NB] bf16
    float*          AGG  = (float*)(HB + (size_t)NXF);         // [N_ATOMS][NB] fp32
    float*          U    = AGG + (size_t)NXF;                  // [N_EDGES]
    unsigned short* Tab0 = (unsigned short*)(U + N_EDGES);     // [2050][NB] bf16
    unsigned short* Tab1 = Tab0 + (size_t)2050 * NB;
    short*          Wimg = (short*)(Tab1 + (size_t)2050 * NB); // 9 x 32768 (w=0 unused)

    k_pre0<<<P0_GEMM + P0_ZERO + P0_TAB + P0_DST + P0_WPR, 256, 0, stream>>>(
        z, emb, rij, in2f, oW1, oW2,
        fW1, fb1, fW2, fb2, HB, Tab0, AGG, U, Wimg);

    for (int l = 0; l < NLAYERS; ++l) {
        unsigned short* TabCur = (l & 1) ? Tab1 : Tab0;
        unsigned short* TabNxt = (l & 1) ? Tab0 : Tab1;
        int ln = (l < NLAYERS - 1) ? l + 1 : 0;     // next-layer filter params (dummy on last)
        int grid_e = EBLKS + ((l < NLAYERS - 1) ? TABBLKS : 0);

        k_edge<<<grid_e, 256, 0, stream>>>(U, ii, jj,
                                           (const unsigned*)HB,
                                           (const unsigned*)TabCur,
                                           AGG,
                                           fW1 + (size_t)ln * NRBF * NB,
                                           fb1 + (size_t)ln * NB,
                                           fW2 + (size_t)ln * NB * NB,
                                           fb2 + (size_t)ln * NB,
                                           TabNxt);

        const short* img1  = Wimg + (size_t)(l * 3 + 1) * 32768;
        const short* img2  = Wimg + (size_t)(l * 3 + 2) * 32768;
        const short* img0n = Wimg + (size_t)(((l + 1) % 3) * 3) * 32768 + 3 * 32768; // in2f(l+1) = w=(l+1)*3
        img0n = Wimg + (size_t)((l + 1 < NLAYERS ? (l + 1) * 3 : 3)) * 32768;

        if (l == 0)
            k_fuse<1, 0><<<N_ATOMS / 64, 256, 0, stream>>>(AGG, img1, ob1 + (size_t)l * NB,
                                                           img2, ob2 + (size_t)l * NB,
                                                           img0n, z, emb, X, HB);
        else if (l < NLAYERS - 1)
            k_fuse<0, 0><<<N_ATOMS / 64, 256, 0, stream>>>(AGG, img1, ob1 + (size_t)l * NB,
                                                           img2, ob2 + (size_t)l * NB,
                                                           img0n, z, emb, X, HB);
        else
            k_fuse<0, 1><<<N_ATOMS / 64, 256, 0, stream>>>(AGG, img1, ob1 + (size_t)l * NB,
                                                           img2, ob2 + (size_t)l * NB,
                                                           img0n, z, emb, X, HB);
    }
}

// Round 9
// 226.913 us; speedup vs baseline: 3.4080x; 1.1250x over previous
//
#include <hip/hip_runtime.h>
#include <math.h>

#define N_ATOMS 40000
#define N_EDGES 640000
#define NB      128
#define NRBF    20
#define NLAYERS 3
#define CUTOFF  5.0f
#define DELTA   (CUTOFF / 19.0f)
#define RBF_COEFF (-0.5f / (DELTA * DELTA))
#define LN2F    0.69314718055994531f

#define KTAB    2048
#define TSCALE  ((float)KTAB / CUTOFF)
#define EPB     256
#define EBLKS   (N_EDGES / EPB)         // 2500
#define TABBLKS 1025                    // rows 0..2049, 2 per block

typedef __attribute__((ext_vector_type(8))) short bf16x8;
typedef __attribute__((ext_vector_type(4))) short bf16x4;
typedef __attribute__((ext_vector_type(4))) float fx4;

__device__ __forceinline__ float ssp_f(float x) {
    return fmaxf(x, 0.f) + __logf(1.f + __expf(-fabsf(x))) - LN2F;
}

__device__ __forceinline__ unsigned short bf16_rne(float x) {
    unsigned u = __float_as_uint(x);
    unsigned r = u + 0x7fffu + ((u >> 16) & 1u);
    return (unsigned short)(r >> 16);
}

__device__ __forceinline__ float bfl(unsigned u) { return __uint_as_float(u << 16); }
__device__ __forceinline__ float bfh(unsigned u) { return __uint_as_float(u & 0xffff0000u); }

// ---- GEMM building blocks (plain bf16) ----

// stage fp32 A-tile chunk (64 rows x 64 k) -> bf16, swizzled
__device__ __forceinline__ void stage_A_f32(const float* __restrict__ A, int row0, int kc,
                                            short* Ah, int tid) {
    #pragma unroll
    for (int it = 0; it < 4; ++it) {
        int idx4 = tid + it * 256;
        int r = idx4 >> 4, kq = (idx4 & 15) << 2;
        float4 v = *(const float4*)(A + (size_t)(row0 + r) * NB + kc * 64 + kq);
        bf16x4 hs;
        const float* vf = (const float*)&v;
        #pragma unroll
        for (int j = 0; j < 4; ++j) hs[j] = (short)bf16_rne(vf[j]);
        int wi = r * 64 + (kq ^ ((r & 7) << 3));
        *(bf16x4*)(Ah + wi) = hs;
    }
}

// stage AGG chunk and zero it behind the read (next-layer prep)
template<int ZERO>
__device__ __forceinline__ void stage_A_agg(float* __restrict__ A, int row0, int kc,
                                            short* Ah, int tid) {
    #pragma unroll
    for (int it = 0; it < 4; ++it) {
        int idx4 = tid + it * 256;
        int r = idx4 >> 4, kq = (idx4 & 15) << 2;
        float* src = A + (size_t)(row0 + r) * NB + kc * 64 + kq;
        float4 v = *(const float4*)src;
        if (ZERO) *(float4*)src = make_float4(0.f, 0.f, 0.f, 0.f);
        bf16x4 hs;
        const float* vf = (const float*)&v;
        #pragma unroll
        for (int j = 0; j < 4; ++j) hs[j] = (short)bf16_rne(vf[j]);
        int wi = r * 64 + (kq ^ ((r & 7) << 3));
        *(bf16x4*)(Ah + wi) = hs;
    }
}

// stage A from embedding gather (layer 0 GEMM0)
__device__ __forceinline__ void stage_A_emb(const float* __restrict__ emb,
                                            const int* __restrict__ z, int row0, int kc,
                                            short* Ah, int tid) {
    #pragma unroll
    for (int it = 0; it < 4; ++it) {
        int idx4 = tid + it * 256;
        int r = idx4 >> 4, kq = (idx4 & 15) << 2;
        int zr = z[row0 + r];
        float4 v = *(const float4*)(emb + (size_t)zr * NB + kc * 64 + kq);
        bf16x4 hs;
        const float* vf = (const float*)&v;
        #pragma unroll
        for (int j = 0; j < 4; ++j) hs[j] = (short)bf16_rne(vf[j]);
        int wi = r * 64 + (kq ^ ((r & 7) << 3));
        *(bf16x4*)(Ah + wi) = hs;
    }
}

// copy one pre-swizzled weight chunk image (128 cols x 64 k) to LDS
__device__ __forceinline__ void stage_W(const short* __restrict__ imgh,
                                        short* Wh, int tid) {
    #pragma unroll
    for (int it = 0; it < 4; ++it) {
        int i = tid + it * 256;
        ((bf16x8*)Wh)[i] = ((const bf16x8*)imgh)[i];
    }
}

// stage W chunk directly from fp32 W[k][col] (layer-0 GEMM0 only)
__device__ __forceinline__ void stage_W_f32(const float* __restrict__ W, int kc,
                                            short* Wh, int tid) {
    #pragma unroll
    for (int it = 0; it < 8; ++it) {
        int i = tid + it * 256;            // 0..2047
        int kl = i >> 5;                   // 0..63
        int c0 = (i & 31) << 2;
        float4 v = *(const float4*)(W + (size_t)(kc * 64 + kl) * NB + c0);
        const float* vf = (const float*)&v;
        #pragma unroll
        for (int j = 0; j < 4; ++j) {
            int col = c0 + j;
            Wh[col * 64 + (kl ^ ((col & 7) << 3))] = (short)bf16_rne(vf[j]);
        }
    }
}

// one K=64 chunk of bf16 MFMA: acc += A_chunk @ W_chunk (16 MFMA/wave)
__device__ __forceinline__ void g_compute(const short* AH, int choff,
                                          const short* Wh,
                                          int wr, int wc, int lane, fx4 acc[2][4]) {
    #pragma unroll
    for (int ks = 0; ks < 2; ++ks) {
        int kb = ks * 32 + (lane >> 4) * 8;
        bf16x8 a_h[2];
        #pragma unroll
        for (int s = 0; s < 2; ++s) {
            int r = wr + s * 16 + (lane & 15);
            int idx = choff + r * 64 + (kb ^ ((r & 7) << 3));
            a_h[s] = *(const bf16x8*)(AH + idx);
        }
        #pragma unroll
        for (int c = 0; c < 4; ++c) {
            int col = wc + c * 16 + (lane & 15);
            int idx = col * 64 + (kb ^ ((col & 7) << 3));
            bf16x8 b_h = *(const bf16x8*)(Wh + idx);
            #pragma unroll
            for (int s = 0; s < 2; ++s)
                acc[s][c] = __builtin_amdgcn_mfma_f32_16x16x32_bf16(a_h[s], b_h, acc[s][c], 0, 0, 0);
        }
    }
}

// write packed table pair words: Tab2[r].x = v_r, Tab2[r-1].y = v_r
// tv: LDS [2][128] fp32 values for rows (tb*2, tb*2+1)
__device__ __forceinline__ void tab_pack_store(const float* tv, int tb, int tid,
                                               unsigned* __restrict__ TabW) {
    int half = tid >> 7, f = tid & 127;
    if (f < 64) {
        int rr = tb * 2 + half;
        unsigned pk = (unsigned)bf16_rne(tv[half * 128 + 2 * f])
                    | ((unsigned)bf16_rne(tv[half * 128 + 2 * f + 1]) << 16);
        TabW[((size_t)rr * 64 + f) * 2] = pk;                       // .x of rr
        if (rr > 0) TabW[((size_t)(rr - 1) * 64 + f) * 2 + 1] = pk; // .y of rr-1
    }
}

// ---- k_pre0: layer-0 GEMM0 + zero AGG + table0 + dist + wprep(w=1..8) ----
#define P0_GEMM 625
#define P0_ZERO 1250
#define P0_TAB  1025
#define P0_DST  625
#define P0_WPR  64
__global__ __launch_bounds__(256) void k_pre0(const int* __restrict__ z,
                                              const float* __restrict__ emb,
                                              const float* __restrict__ r_ij,
                                              const float* __restrict__ in2f,
                                              const float* __restrict__ oW1,
                                              const float* __restrict__ oW2,
                                              const float* __restrict__ fW1,
                                              const float* __restrict__ fb1,
                                              const float* __restrict__ fW2,
                                              const float* __restrict__ fb2,
                                              unsigned short* __restrict__ HB,
                                              unsigned* __restrict__ TabW,
                                              float* __restrict__ AGG,
                                              float* __restrict__ U,
                                              short* __restrict__ Wimg) {
    __shared__ short APOOL[12288];               // 24 KB
    int bid = blockIdx.x, tid = threadIdx.x;

    if (bid < P0_GEMM) {
        short* Ah = APOOL;                       // 4096
        short* Wh = APOOL + 4096;                // 8192
        int wave = tid >> 6, lane = tid & 63;
        int wr = (wave & 1) * 32, wc = (wave >> 1) * 64;
        int row0 = bid * 64;
        fx4 acc[2][4];
        #pragma unroll
        for (int s = 0; s < 2; ++s)
            #pragma unroll
            for (int c = 0; c < 4; ++c)
                acc[s][c] = (fx4){0.f, 0.f, 0.f, 0.f};
        for (int kc = 0; kc < 2; ++kc) {
            if (kc) __syncthreads();
            stage_A_emb(emb, z, row0, kc, Ah, tid);
            stage_W_f32(in2f, kc, Wh, tid);
            __syncthreads();
            g_compute(Ah, 0, Wh, wr, wc, lane, acc);
        }
        #pragma unroll
        for (int s = 0; s < 2; ++s)
            #pragma unroll
            for (int c = 0; c < 4; ++c) {
                int colg = wc + c * 16 + (lane & 15);
                #pragma unroll
                for (int reg = 0; reg < 4; ++reg) {
                    int rowg = row0 + wr + s * 16 + (lane >> 4) * 4 + reg;
                    HB[(size_t)rowg * NB + colg] = bf16_rne(acc[s][c][reg]);
                }
            }
    } else if (bid < P0_GEMM + P0_ZERO) {
        int base = (bid - P0_GEMM) * 4096 + tid * 16;
        float4 zv = make_float4(0.f, 0.f, 0.f, 0.f);
        float4* p = (float4*)(AGG + base);
        p[0] = zv; p[1] = zv; p[2] = zv; p[3] = zv;
    } else if (bid < P0_GEMM + P0_ZERO + P0_TAB) {
        int tb = bid - (P0_GEMM + P0_ZERO);
        int half = tid >> 7, f = tid & 127;
        int r = tb * 2 + half;                   // 0..2049
        float* tl = (float*)APOOL;               // [2][128] ssp intermediates
        float* tv = tl + 256;                    // [2][128] final values
        float val = 0.f;
        float d = (float)r * (CUTOFF / (float)KTAB);
        if (r < KTAB) {
            float a = fb1[f];
            #pragma unroll
            for (int q = 0; q < NRBF; ++q) {
                float dr = d - (float)q * DELTA;
                a += __expf(RBF_COEFF * dr * dr) * fW1[q * NB + f];
            }
            tl[half * NB + f] = ssp_f(a);
        }
        __syncthreads();
        if (r < KTAB) {
            float w = fb2[f];
            #pragma unroll 4
            for (int k = 0; k < NB; ++k) w += tl[half * NB + k] * fW2[k * NB + f];
            float rc = 0.5f * (__cosf(d * ((float)M_PI / CUTOFF)) + 1.f);
            val = w * rc;
        }
        tv[half * NB + f] = val;
        __syncthreads();
        tab_pack_store(tv, tb, tid, TabW);
    } else if (bid < P0_GEMM + P0_ZERO + P0_TAB + P0_DST) {
        int e = (bid - (P0_GEMM + P0_ZERO + P0_TAB)) * 1024 + tid * 4;
        const float4* rv = (const float4*)(r_ij + (size_t)e * 3);
        float4 a = rv[0], b = rv[1], c = rv[2];
        float d0 = sqrtf(a.x * a.x + a.y * a.y + a.z * a.z);
        float d1 = sqrtf(a.w * a.w + b.x * b.x + b.y * b.y);
        float d2 = sqrtf(b.z * b.z + b.w * b.w + c.x * c.x);
        float d3 = sqrtf(c.y * c.y + c.z * c.z + c.w * c.w);
        *(float4*)(U + e) = make_float4(d0 * TSCALE, d1 * TSCALE, d2 * TSCALE, d3 * TSCALE);
    } else {
        int b2 = bid - (P0_GEMM + P0_ZERO + P0_TAB + P0_DST);   // 0..63
        int w = 1 + (b2 >> 3), seg = b2 & 7;                    // images 1..8
        int layer = w / 3, which = w % 3;
        const float* W = (which == 0 ? in2f : which == 1 ? oW1 : oW2)
                         + (size_t)layer * NB * NB;
        short* hi = Wimg + (size_t)w * 16384;
        int i0 = seg * 2048;
        #pragma unroll
        for (int ofs = 0; ofs < 2048; ofs += 256) {
            int i = i0 + ofs + tid;
            int k = i >> 7, col = i & 127;
            int kc = k >> 6, kl = k & 63;
            hi[kc * 8192 + col * 64 + (kl ^ ((col & 7) << 3))] = (short)bf16_rne(W[i]);
        }
    }
}

// ---- edge kernel (dual-stream, packed-pair table) + appended next-layer table ----
__global__ __launch_bounds__(256) void k_edge(const float* __restrict__ U,
                                              const int* __restrict__ idx_i,
                                              const int* __restrict__ idx_j,
                                              const unsigned* __restrict__ HBv,
                                              const uint2* __restrict__ TabP,
                                              float* __restrict__ AGG,
                                              const float* __restrict__ nW1,
                                              const float* __restrict__ nb1,
                                              const float* __restrict__ nW2,
                                              const float* __restrict__ nb2,
                                              unsigned* __restrict__ TabN) {
    __shared__ float u_s[EPB];
    __shared__ int   i_s[EPB];
    __shared__ int   j_s[EPB];
    __shared__ float t_lds[256];
    __shared__ float tv_lds[256];
    int tid = threadIdx.x;
    int bid = blockIdx.x;

    if (bid >= EBLKS) {                        // next-layer table block
        int tb = bid - EBLKS;
        int half = tid >> 7, f = tid & 127;
        int r = tb * 2 + half;
        float val = 0.f;
        float d = (float)r * (CUTOFF / (float)KTAB);
        if (r < KTAB) {
            float a = nb1[f];
            #pragma unroll
            for (int q = 0; q < NRBF; ++q) {
                float dr = d - (float)q * DELTA;
                a += __expf(RBF_COEFF * dr * dr) * nW1[q * NB + f];
            }
            t_lds[half * NB + f] = ssp_f(a);
        }
        __syncthreads();
        if (r < KTAB) {
            float w = nb2[f];
            #pragma unroll 4
            for (int k = 0; k < NB; ++k) w += t_lds[half * NB + k] * nW2[k * NB + f];
            float rc = 0.5f * (__cosf(d * ((float)M_PI / CUTOFF)) + 1.f);
            val = w * rc;
        }
        tv_lds[half * NB + f] = val;
        __syncthreads();
        tab_pack_store(tv_lds, tb, tid, TabN);
        return;
    }

    int e0 = bid * EPB;
    u_s[tid] = U[e0 + tid];
    i_s[tid] = idx_i[e0 + tid];
    j_s[tid] = idx_j[e0 + tid];
    __syncthreads();

    int wave = tid >> 6, lane = tid & 63;
    int wbase = wave << 6;

    float axA = 0.f, ayA = 0.f, axB = 0.f, ayB = 0.f;
    int curA = -1, curB = -1;
    int nfA = 0, nfB = 0;

    #pragma unroll 2
    for (int t = 0; t < 32; ++t) {
        int eA = wbase + t;
        int eB = wbase + 32 + t;
        float uA = u_s[eA], uB = u_s[eB];
        int   iaA = i_s[eA], iaB = i_s[eB];
        int   jaA = j_s[eA], jaB = j_s[eB];

        int kA = (int)uA; kA = (kA > KTAB) ? KTAB : kA;
        int kB = (int)uB; kB = (kB > KTAB) ? KTAB : kB;
        float frA = uA - (float)kA;
        float frB = uB - (float)kB;

        uint2 tpA = TabP[(size_t)kA * 64 + lane];
        uint2 tpB = TabP[(size_t)kB * 64 + lane];
        unsigned hqA = HBv[(size_t)jaA * 64 + lane];
        unsigned hqB = HBv[(size_t)jaB * 64 + lane];

        float w0A = fmaf(frA, bfl(tpA.y) - bfl(tpA.x), bfl(tpA.x));
        float w1A = fmaf(frA, bfh(tpA.y) - bfh(tpA.x), bfh(tpA.x));
        float w0B = fmaf(frB, bfl(tpB.y) - bfl(tpB.x), bfl(tpB.x));
        float w1B = fmaf(frB, bfh(tpB.y) - bfh(tpB.x), bfh(tpB.x));

        if (iaA != curA) {
            if (curA >= 0) {
                float* p = AGG + (size_t)curA * NB + 2 * lane;
                if (nfA == 0) { atomicAdd(p, axA); atomicAdd(p + 1, ayA); }
                else          { *(float2*)p = make_float2(axA, ayA); }
                ++nfA;
            }
            axA = 0.f; ayA = 0.f;
            curA = iaA;
        }
        axA = fmaf(bfl(hqA), w0A, axA);
        ayA = fmaf(bfh(hqA), w1A, ayA);

        if (iaB != curB) {
            if (curB >= 0) {
                float* p = AGG + (size_t)curB * NB + 2 * lane;
                if (nfB == 0) { atomicAdd(p, axB); atomicAdd(p + 1, ayB); }
                else          { *(float2*)p = make_float2(axB, ayB); }
                ++nfB;
            }
            axB = 0.f; ayB = 0.f;
            curB = iaB;
        }
        axB = fmaf(bfl(hqB), w0B, axB);
        ayB = fmaf(bfh(hqB), w1B, ayB);
    }
    if (curA >= 0) {
        float* p = AGG + (size_t)curA * NB + 2 * lane;
        atomicAdd(p, axA); atomicAdd(p + 1, ayA);
    }
    if (curB >= 0) {
        float* p = AGG + (size_t)curB * NB + 2 * lane;
        atomicAdd(p, axB); atomicAdd(p + 1, ayB);
    }
}

// ---- k_fuse: X (+)= ssp(AGG@W1+b1)@W2+b2, zero AGG behind read,
//      then HB = bf16(X_new @ in2f_next) from registers/LDS ----
template<int FIRST, int LAST>
__global__ __launch_bounds__(256) void k_fuse(float* __restrict__ AGG,
                                              const short* __restrict__ img1,
                                              const float* __restrict__ b1,
                                              const short* __restrict__ img2,
                                              const float* __restrict__ b2,
                                              const short* __restrict__ img0n,
                                              const int* __restrict__ z,
                                              const float* __restrict__ emb,
                                              float* __restrict__ X,
                                              unsigned short* __restrict__ HB) {
    __shared__ short POOL[16384];              // 32 KB
    short* Ah = POOL;                          // 4096 (GEMM1 A chunk)
    short* Th = POOL;                          // 8192 (T / X_new, 2 chunks)
    short* Wh = POOL + 8192;                   // 8192 (W chunk)

    int tid = threadIdx.x;
    int wave = tid >> 6, lane = tid & 63;
    int wr = (wave & 1) * 32, wc = (wave >> 1) * 64;
    int row0 = blockIdx.x * 64;

    // GEMM1: accT = AGG @ W1 (+ zero AGG behind read unless LAST)
    fx4 accT[2][4];
    #pragma unroll
    for (int s = 0; s < 2; ++s)
        #pragma unroll
        for (int c = 0; c < 4; ++c)
            accT[s][c] = (fx4){0.f, 0.f, 0.f, 0.f};
    for (int kc = 0; kc < 2; ++kc) {
        if (kc) __syncthreads();
        stage_A_agg<!LAST>(AGG, row0, kc, Ah, tid);
        stage_W(img1 + kc * 8192, Wh, tid);
        __syncthreads();
        g_compute(Ah, 0, Wh, wr, wc, lane, accT);
    }
    __syncthreads();

    // T = ssp(accT + b1) -> LDS bf16 (both chunks); stage W2 chunk 0
    #pragma unroll
    for (int s = 0; s < 2; ++s)
        #pragma unroll
        for (int c = 0; c < 4; ++c) {
            int colg = wc + c * 16 + (lane & 15);
            float bv = b1[colg];
            int kc2 = colg >> 6, kl = colg & 63;
            #pragma unroll
            for (int reg = 0; reg < 4; ++reg) {
                int rl = wr + s * 16 + (lane >> 4) * 4 + reg;
                float t = ssp_f(accT[s][c][reg] + bv);
                Th[kc2 * 4096 + rl * 64 + (kl ^ ((rl & 7) << 3))] = (short)bf16_rne(t);
            }
        }
    stage_W(img2, Wh, tid);
    __syncthreads();

    // GEMM2: accV = T @ W2
    fx4 accV[2][4];
    #pragma unroll
    for (int s = 0; s < 2; ++s)
        #pragma unroll
        for (int c = 0; c < 4; ++c)
            accV[s][c] = (fx4){0.f, 0.f, 0.f, 0.f};
    g_compute(Th, 0, Wh, wr, wc, lane, accV);
    __syncthreads();
    stage_W(img2 + 8192, Wh, tid);
    __syncthreads();
    g_compute(Th, 4096, Wh, wr, wc, lane, accV);
    __syncthreads();                           // T dead; region reused for X_new

    // epilogue: X_new = X_old + accV + b2; write X; stage X_new for GEMM3
    #pragma unroll
    for (int s = 0; s < 2; ++s)
        #pragma unroll
        for (int c = 0; c < 4; ++c) {
            int colg = wc + c * 16 + (lane & 15);
            float bv = b2[colg];
            int kc2 = colg >> 6, kl = colg & 63;
            #pragma unroll
            for (int reg = 0; reg < 4; ++reg) {
                int rowg = row0 + wr + s * 16 + (lane >> 4) * 4 + reg;
                size_t o = (size_t)rowg * NB + colg;
                float xo;
                if (FIRST) xo = emb[(size_t)z[rowg] * NB + colg];
                else       xo = X[o];
                float xn = xo + accV[s][c][reg] + bv;
                X[o] = xn;
                if (!LAST) {
                    int rl = wr + s * 16 + (lane >> 4) * 4 + reg;
                    Th[kc2 * 4096 + rl * 64 + (kl ^ ((rl & 7) << 3))] = (short)bf16_rne(xn);
                }
            }
        }
    if (LAST) return;

    // GEMM3: HB = bf16(X_new @ in2f_next)
    stage_W(img0n, Wh, tid);
    __syncthreads();
    fx4 accH[2][4];
    #pragma unroll
    for (int s = 0; s < 2; ++s)
        #pragma unroll
        for (int c = 0; c < 4; ++c)
            accH[s][c] = (fx4){0.f, 0.f, 0.f, 0.f};
    g_compute(Th, 0, Wh, wr, wc, lane, accH);
    __syncthreads();
    stage_W(img0n + 8192, Wh, tid);
    __syncthreads();
    g_compute(Th, 4096, Wh, wr, wc, lane, accH);

    #pragma unroll
    for (int s = 0; s < 2; ++s)
        #pragma unroll
        for (int c = 0; c < 4; ++c) {
            int colg = wc + c * 16 + (lane & 15);
            #pragma unroll
            for (int reg = 0; reg < 4; ++reg) {
                int rowg = row0 + wr + s * 16 + (lane >> 4) * 4 + reg;
                HB[(size_t)rowg * NB + colg] = bf16_rne(accH[s][c][reg]);
            }
        }
}

extern "C" void kernel_launch(void* const* d_in, const int* in_sizes, int n_in,
                              void* d_out, int out_size, void* d_ws, size_t ws_size,
                              hipStream_t stream) {
    const int*   z    = (const int*)  d_in[0];
    const float* rij  = (const float*)d_in[1];
    const int*   ii   = (const int*)  d_in[2];
    const int*   jj   = (const int*)  d_in[3];
    const float* emb  = (const float*)d_in[4];
    const float* in2f = (const float*)d_in[5];
    const float* fW1  = (const float*)d_in[6];
    const float* fb1  = (const float*)d_in[7];
    const float* fW2  = (const float*)d_in[8];
    const float* fb2  = (const float*)d_in[9];
    const float* oW1  = (const float*)d_in[10];
    const float* ob1  = (const float*)d_in[11];
    const float* oW2  = (const float*)d_in[12];
    const float* ob2  = (const float*)d_in[13];

    const int NXF = N_ATOMS * NB;

    float* X = (float*)d_out;
    unsigned short* HB   = (unsigned short*)d_ws;              // [N_ATOMS][NB] bf16
    float*          AGG  = (float*)(HB + (size_t)NXF);         // [N_ATOMS][NB] fp32
    float*          U    = AGG + (size_t)NXF;                  // [N_EDGES]
    unsigned*       Tab0 = (unsigned*)(U + N_EDGES);           // [2050][64] uint2
    unsigned*       Tab1 = Tab0 + (size_t)2050 * 128;
    short*          Wimg = (short*)(Tab1 + (size_t)2050 * 128); // 9 x 16384 (w=0 unused)

    k_pre0<<<P0_GEMM + P0_ZERO + P0_TAB + P0_DST + P0_WPR, 256, 0, stream>>>(
        z, emb, rij, in2f, oW1, oW2,
        fW1, fb1, fW2, fb2, HB, Tab0, AGG, U, Wimg);

    for (int l = 0; l < NLAYERS; ++l) {
        unsigned* TabCur = (l & 1) ? Tab1 : Tab0;
        unsigned* TabNxt = (l & 1) ? Tab0 : Tab1;
        int ln = (l < NLAYERS - 1) ? l + 1 : 0;
        int grid_e = EBLKS + ((l < NLAYERS - 1) ? TABBLKS : 0);

        k_edge<<<grid_e, 256, 0, stream>>>(U, ii, jj,
                                           (const unsigned*)HB,
                                           (const uint2*)TabCur,
                                           AGG,
                                           fW1 + (size_t)ln * NRBF * NB,
                                           fb1 + (size_t)ln * NB,
                                           fW2 + (size_t)ln * NB * NB,
                                           fb2 + (size_t)ln * NB,
                                           TabNxt);

        const short* img1  = Wimg + (size_t)(l * 3 + 1) * 16384;
        const short* img2  = Wimg + (size_t)(l * 3 + 2) * 16384;
        const short* img0n = Wimg + (size_t)((l + 1 < NLAYERS ? (l + 1) * 3 : 3)) * 16384;

        if (l == 0)
            k_fuse<1, 0><<<N_ATOMS / 64, 256, 0, stream>>>(AGG, img1, ob1 + (size_t)l * NB,
                                                           img2, ob2 + (size_t)l * NB,
                                                           img0n, z, emb, X, HB);
        else if (l < NLAYERS - 1)
            k_fuse<0, 0><<<N_ATOMS / 64, 256, 0, stream>>>(AGG, img1, ob1 + (size_t)l * NB,
                                                           img2, ob2 + (size_t)l * NB,
                                                           img0n, z, emb, X, HB);
        else
            k_fuse<0, 1><<<N_ATOMS / 64, 256, 0, stream>>>(AGG, img1, ob1 + (size_t)l * NB,
                                                           img2, ob2 + (size_t)l * NB,
                                                           img0n, z, emb, X, HB);
    }
}